// Round 2
// baseline (722.979 us; speedup 1.0000x reference)
//
#include <hip/hip_runtime.h>
#include <stdint.h>

typedef __bf16 bf16;
typedef bf16 bf16x8 __attribute__((ext_vector_type(8)));
typedef float f32x4 __attribute__((ext_vector_type(4)));

#define B_  4
#define L_  4096
#define DM  1024
#define DS  256
#define DH  4096
#define BL  16384   // B_*L_
#define CL  64      // scan chunk length
#define NC  64      // chunks per sequence

__device__ __forceinline__ float bfbits(uint32_t lo16) {
  union { uint32_t u; float f; } v; v.u = lo16 << 16; return v.f;
}

__device__ __forceinline__ void async16(const bf16* g, bf16* l) {
  __builtin_amdgcn_global_load_lds(
      (const __attribute__((address_space(1))) uint32_t*)g,
      (__attribute__((address_space(3))) uint32_t*)l, 16, 0, 0);
}

// ---------------- Phase A ----------------
__global__ void phaseA(const float* __restrict__ nu_log,
                       const float* __restrict__ th_log,
                       float* __restrict__ scal) {
  int n = threadIdx.x;
  float nu = __expf(nu_log[n]);
  float th = __expf(th_log[n]);
  float mod = __expf(-nu);
  float lr = mod * cosf(th);
  float li = mod * sinf(th);
  float g = sqrtf(fmaxf(1.0f - mod * mod, 0.0f));
  float pr = 1.f, pi = 0.f;
  for (int i = 0; i < CL; i++) {
    float nr = pr * lr - pi * li;
    float ni = pr * li + pi * lr;
    pr = nr; pi = ni;
  }
  scal[n] = lr; scal[256 + n] = li;
  scal[512 + n] = pr; scal[768 + n] = pi;
  scal[1024 + n] = g;
}

// ---------------- Weight prep ----------------
__global__ void prep_bu(const float* __restrict__ B_re, const float* __restrict__ B_im,
                        const float* __restrict__ scal, bf16* __restrict__ WB) {
  size_t i = (size_t)blockIdx.x * 256 + threadIdx.x;   // over 512*1024
  int row = (int)(i >> 10), col = (int)(i & 1023);
  int n = row >> 1;
  const float* src = (row & 1) ? B_im : B_re;
  WB[i] = (bf16)(scal[1024 + n] * src[n * 1024 + col]);
}

__global__ void prep_y(const float* __restrict__ C_re, const float* __restrict__ C_im,
                       const float* __restrict__ D_mat, bf16* __restrict__ WB) {
  size_t i = (size_t)blockIdx.x * 256 + threadIdx.x;   // over 1024*1536
  int m = (int)(i / 1536), c = (int)(i % 1536);
  float v;
  if (c < 256)       v = C_re[m * 256 + c];
  else if (c < 512)  v = -C_im[m * 256 + (c - 256)];
  else               v = D_mat[m * 1024 + (c - 512)];
  WB[i] = (bf16)v;
}

__global__ void transpose_to_bf16(const float* __restrict__ in, bf16* __restrict__ out,
                                  int R, int C) {
  __shared__ float tile[32][33];
  int c0 = blockIdx.x * 32, r0 = blockIdx.y * 32;
  int tx = threadIdx.x, ty = threadIdx.y;
  for (int i = 0; i < 32; i += 8)
    tile[ty + i][tx] = in[(size_t)(r0 + ty + i) * C + c0 + tx];
  __syncthreads();
  for (int i = 0; i < 32; i += 8)
    out[(size_t)(c0 + ty + i) * R + r0 + tx] = (bf16)tile[tx][ty + i];
}

__global__ void conv_x(const float4* __restrict__ x, bf16* __restrict__ XS) {
  size_t i = (size_t)blockIdx.x * 256 + threadIdx.x;  // float4 index
  size_t t = i >> 8;
  int d4 = (int)(i & 255);
  float4 v = x[i];
  bf16* o = XS + t * 1536 + 512 + (size_t)d4 * 4;
  o[0] = (bf16)v.x; o[1] = (bf16)v.y; o[2] = (bf16)v.z; o[3] = (bf16)v.w;
}

// ---------------- GEMM: C[m,n] = sum_k A[m,k] * Bt[n,k] ----------------
// 256x256 tile, BK=64, 8 waves (2M x 4N), per-wave 128x64 output (8x4 mfma
// 16x16x32). 8-phase schedule: per phase {ds_read subtile | stage 1 half-tile
// via global_load_lds | barrier | lgkmcnt(0) | setprio(1) 16xMFMA setprio(0) |
// barrier}. Counted vmcnt(6) once per K-tile (3 half-tiles in flight across
// barriers); vmcnt(0) only before the final K-tile.
// LDS: [2 dbuf][2 half][128][64] bf16 per operand = 128 KiB total.
// Swizzle: within a [128][64]-elem half-tile, logical elem (row, c) lives at
// phys col c ^ ((row & 12) << 2). Applied on the GLOBAL source during staging
// (LDS dest stays linear, global_load_lds requirement) and on every ds_read
// column offset. NOTE: the XOR must wrap the FULL column offset including the
// +32 second-K-half shift (qx1) -- bit 5 of the swizzle otherwise carries out
// of the row (round-1 NaN bug).
// EPI: 0 = store bf16, 1 = gelu->bf16, 2 = out = xres + sigmoid(reslog)*acc (f32)
#define SYNC_PRE()  do { asm volatile("" ::: "memory"); __builtin_amdgcn_s_barrier(); } while (0)
#define SYNC_POST() do { __builtin_amdgcn_s_barrier(); asm volatile("" ::: "memory"); } while (0)

template <int EPI>
__global__ __launch_bounds__(512, 2) void gemm256(
    const bf16* __restrict__ A, int lda,
    const bf16* __restrict__ Bt, int ldb,
    void* __restrict__ C, int ldc, int NK, int mt, int nt,
    const float* __restrict__ xres, const float* __restrict__ reslog) {
  __shared__ __align__(16) bf16 sA[2 * 2 * 8192];   // 64 KB
  __shared__ __align__(16) bf16 sB[2 * 2 * 8192];   // 64 KB

  const int tid  = threadIdx.x;
  const int lane = tid & 63;
  const int wave = tid >> 6;
  const int q = lane >> 4, l16 = lane & 15;
  const int wr = wave >> 2, wc = wave & 3;   // 2 x 4 wave grid

  // XCD tile swizzle (nb % 8 == 0 and mt % 8 == 0 for all our shapes)
  int nb = mt * nt;
  int per = nb >> 3;
  int t0 = (blockIdx.x & 7) * per + (blockIdx.x >> 3);
  int gsz = nt << 3;
  int g = t0 / gsz, r = t0 % gsz;
  size_t m0 = (size_t)(g * 8 + (r & 7)) * 256;
  size_t n0 = (size_t)(r >> 3) * 256;

  // ---- staging: thread writes linear LDS bytes tid*16 and tid*16+8192 of a
  // half-tile; source element is the swizzle-inverse (involution) position.
  const int srow = tid >> 3;                                   // 0..63
  const int scol = ((tid & 7) << 3) ^ ((srow & 12) << 2);
  const bf16* gA = A  + (m0 + srow) * (size_t)lda + scol;
  const bf16* gB = Bt + (n0 + srow) * (size_t)ldb + scol;
  bf16* lA = sA + tid * 8;
  bf16* lB = sB + tid * 8;

  auto stageA = [&](int kt, int w) {
    const bf16* s = gA + (size_t)(w * 128) * lda + kt * 64;
    bf16* l = lA + ((kt & 1) * 16384 + w * 8192);
    async16(s, l);
    async16(s + (size_t)64 * lda, l + 4096);
  };
  auto stageB = [&](int kt, int w) {
    const bf16* s = gB + (size_t)(w * 128) * ldb + kt * 64;
    bf16* l = lB + ((kt & 1) * 16384 + w * 8192);
    async16(s, l);
    async16(s + (size_t)64 * ldb, l + 4096);
  };

  // prologue: half-tile stream = kt0{B0,B1,A0,A1}, kt1{B0,B1,A0}
  stageB(0, 0); stageB(0, 1); stageA(0, 0); stageA(0, 1);
  stageB(1, 0); stageB(1, 1); stageA(1, 0);
  __builtin_amdgcn_s_waitcnt(0x0F76);   // vmcnt(6): kt0 fully landed
  __builtin_amdgcn_s_barrier();
  asm volatile("" ::: "memory");

  // per-lane swizzled read column offsets (elements): K-half 0 and K-half 1
  const int sw  = (l16 & 12) << 2;
  const int qx0 = (q << 3) ^ sw;
  const int qx1 = ((q << 3) + 32) ^ sw;
  const bf16* Ard = sA + wr * 8192 + l16 * 64;
  const bf16* Brd = sB + (wc >> 1) * 8192 + ((wc & 1) * 64 + l16) * 64;

  f32x4 acc[8][4] = {};
  bf16x8 a[4][2], b[4][2];

  for (int t = 0; t < NK; ++t) {
    const int d = (t & 1) * 16384;
    const bf16* Ab = Ard + d;
    const bf16* Bb = Brd + d;

    // ---- phase 0: read A rows 0-63 + all B; MFMA quadrant (m0-3, n0-1) ----
#pragma unroll
    for (int j = 0; j < 4; ++j) {
      a[j][0] = *(const bf16x8*)&Ab[j * 1024 + qx0];
      a[j][1] = *(const bf16x8*)&Ab[j * 1024 + qx1];
    }
#pragma unroll
    for (int n = 0; n < 4; ++n) {
      b[n][0] = *(const bf16x8*)&Bb[n * 1024 + qx0];
      b[n][1] = *(const bf16x8*)&Bb[n * 1024 + qx1];
    }
    if (t + 1 < NK) stageA(t + 1, 1);   // last half of kt t+1
    SYNC_PRE();
    asm volatile("s_waitcnt lgkmcnt(0)" ::: "memory");
    __builtin_amdgcn_s_setprio(1);
#pragma unroll
    for (int j = 0; j < 4; ++j)
#pragma unroll
      for (int n = 0; n < 2; ++n) {
        acc[j][n] = __builtin_amdgcn_mfma_f32_16x16x32_bf16(a[j][0], b[n][0], acc[j][n], 0, 0, 0);
        acc[j][n] = __builtin_amdgcn_mfma_f32_16x16x32_bf16(a[j][1], b[n][1], acc[j][n], 0, 0, 0);
      }
    __builtin_amdgcn_s_setprio(0);
    SYNC_POST();

    // ---- phase 1: MFMA quadrant (m0-3, n2-3) ----
    if (t + 2 < NK) stageB(t + 2, 0);
    SYNC_PRE();
    __builtin_amdgcn_s_setprio(1);
#pragma unroll
    for (int j = 0; j < 4; ++j)
#pragma unroll
      for (int n = 0; n < 2; ++n) {
        acc[j][2 + n] = __builtin_amdgcn_mfma_f32_16x16x32_bf16(a[j][0], b[2 + n][0], acc[j][2 + n], 0, 0, 0);
        acc[j][2 + n] = __builtin_amdgcn_mfma_f32_16x16x32_bf16(a[j][1], b[2 + n][1], acc[j][2 + n], 0, 0, 0);
      }
    __builtin_amdgcn_s_setprio(0);
    SYNC_POST();

    // ---- phase 2: read A rows 64-127; MFMA quadrant (m4-7, n0-1) ----
#pragma unroll
    for (int j = 0; j < 4; ++j) {
      a[j][0] = *(const bf16x8*)&Ab[(4 + j) * 1024 + qx0];
      a[j][1] = *(const bf16x8*)&Ab[(4 + j) * 1024 + qx1];
    }
    if (t + 2 < NK) stageB(t + 2, 1);
    SYNC_PRE();
    asm volatile("s_waitcnt lgkmcnt(0)" ::: "memory");
    __builtin_amdgcn_s_setprio(1);
#pragma unroll
    for (int j = 0; j < 4; ++j)
#pragma unroll
      for (int n = 0; n < 2; ++n) {
        acc[4 + j][n] = __builtin_amdgcn_mfma_f32_16x16x32_bf16(a[j][0], b[n][0], acc[4 + j][n], 0, 0, 0);
        acc[4 + j][n] = __builtin_amdgcn_mfma_f32_16x16x32_bf16(a[j][1], b[n][1], acc[4 + j][n], 0, 0, 0);
      }
    __builtin_amdgcn_s_setprio(0);
    SYNC_POST();

    // ---- phase 3: MFMA quadrant (m4-7, n2-3); K-tile boundary vmcnt ----
    if (t + 2 < NK) stageA(t + 2, 0);
    if (t + 2 < NK)      __builtin_amdgcn_s_waitcnt(0x0F76);  // vmcnt(6)
    else if (t + 1 < NK) __builtin_amdgcn_s_waitcnt(0x0F70);  // vmcnt(0)
    SYNC_PRE();
    __builtin_amdgcn_s_setprio(1);
#pragma unroll
    for (int j = 0; j < 4; ++j)
#pragma unroll
      for (int n = 0; n < 2; ++n) {
        acc[4 + j][2 + n] = __builtin_amdgcn_mfma_f32_16x16x32_bf16(a[j][0], b[2 + n][0], acc[4 + j][2 + n], 0, 0, 0);
        acc[4 + j][2 + n] = __builtin_amdgcn_mfma_f32_16x16x32_bf16(a[j][1], b[2 + n][1], acc[4 + j][2 + n], 0, 0, 0);
      }
    __builtin_amdgcn_s_setprio(0);
    SYNC_POST();
  }

  float sig = 0.f;
  if (EPI == 2) sig = 1.f / (1.f + __expf(-reslog[0]));
#pragma unroll
  for (int mi = 0; mi < 8; ++mi)
#pragma unroll
    for (int ni = 0; ni < 4; ++ni) {
      size_t col = n0 + wc * 64 + ni * 16 + l16;
#pragma unroll
      for (int r2 = 0; r2 < 4; ++r2) {
        size_t row = m0 + wr * 128 + mi * 16 + q * 4 + r2;
        float v = acc[mi][ni][r2];
        size_t off = row * (size_t)ldc + col;
        if (EPI == 0) {
          ((bf16*)C)[off] = (bf16)v;
        } else if (EPI == 1) {
          float z = 0.7978845608f * (v + 0.044715f * v * v * v);
          float gv = v / (1.f + __expf(-2.f * z));   // v*0.5*(1+tanh(z))
          ((bf16*)C)[off] = (bf16)gv;
        } else {
          ((float*)C)[off] = xres[off] + sig * v;
        }
      }
    }
}

// ---------------- Scan ----------------
__global__ void scan_pass1(const bf16* __restrict__ Bu, const float* __restrict__ scal,
                           float2* __restrict__ H) {
  int b = blockIdx.x >> 6, c = blockIdx.x & 63, n = threadIdx.x;
  float lr = scal[n], li = scal[256 + n];
  float sr = 0.f, si = 0.f;
  size_t t0 = (size_t)b * L_ + (size_t)c * CL;
  const uint32_t* p = (const uint32_t*)(Bu + t0 * 512) + n;
  for (int j = 0; j < CL; j++) {
    uint32_t u = p[(size_t)j * 256];
    float ur = bfbits(u & 0xffffu), ui = bfbits(u >> 16);
    float nr = lr * sr - li * si + ur;
    float ni = lr * si + li * sr + ui;
    sr = nr; si = ni;
  }
  H[(size_t)(b * NC + c) * 256 + n] = make_float2(sr, si);
}

__global__ void scan_pass2(const float2* __restrict__ H, const float* __restrict__ scal,
                           float2* __restrict__ Carry) {
  int b = blockIdx.x, n = threadIdx.x;
  float Pr = scal[512 + n], Pi = scal[768 + n];
  float cr = 0.f, ci = 0.f;
  for (int c = 0; c < NC; c++) {
    Carry[(size_t)(b * NC + c) * 256 + n] = make_float2(cr, ci);
    float2 h = H[(size_t)(b * NC + c) * 256 + n];
    float nr = Pr * cr - Pi * ci + h.x;
    float ni = Pr * ci + Pi * cr + h.y;
    cr = nr; ci = ni;
  }
}

// st layout: PLANAR-GLOBAL — st[0..1023] = re (b-major), st[1024..2047] = im
__global__ void scan_pass3(const bf16* __restrict__ Bu, const float* __restrict__ scal,
                           const float2* __restrict__ Carry, bf16* __restrict__ XS,
                           float* __restrict__ st) {
  int b = blockIdx.x >> 6, c = blockIdx.x & 63, n = threadIdx.x;
  float lr = scal[n], li = scal[256 + n];
  float2 cv = Carry[(size_t)(b * NC + c) * 256 + n];
  float sr = cv.x, si = cv.y;
  size_t t0 = (size_t)b * L_ + (size_t)c * CL;
  const uint32_t* p = (const uint32_t*)(Bu + t0 * 512) + n;
  bf16* qp = XS + t0 * 1536 + n;
  for (int j = 0; j < CL; j++) {
    uint32_t u = p[(size_t)j * 256];
    float ur = bfbits(u & 0xffffu), ui = bfbits(u >> 16);
    float nr = lr * sr - li * si + ur;
    float ni = lr * si + li * sr + ui;
    sr = nr; si = ni;
    qp[(size_t)j * 1536] = (bf16)sr;
    qp[(size_t)j * 1536 + 256] = (bf16)si;
  }
  if (c == NC - 1) {
    st[(size_t)b * 256 + n] = sr;
    st[1024 + (size_t)b * 256 + n] = si;
  }
}

// ---------------- Launch ----------------
extern "C" void kernel_launch(void* const* d_in, const int* in_sizes, int n_in,
                              void* d_out, int out_size, void* d_ws, size_t ws_size,
                              hipStream_t stream) {
  const float* x      = (const float*)d_in[0];
  const float* nu_log = (const float*)d_in[1];
  const float* th_log = (const float*)d_in[2];
  const float* B_re   = (const float*)d_in[3];
  const float* B_im   = (const float*)d_in[4];
  const float* C_re   = (const float*)d_in[5];
  const float* C_im   = (const float*)d_in[6];
  const float* D_mat  = (const float*)d_in[7];
  const float* W1     = (const float*)d_in[8];
  const float* W2     = (const float*)d_in[9];
  const float* reslog = (const float*)d_in[10];

  char* wsb = (char*)d_ws;
  size_t off = 0;
  auto alloc = [&](size_t bytes) {
    void* p = wsb + off;
    off += (bytes + 255) & ~(size_t)255;
    return p;
  };
  float*  scal = (float*)alloc(5 * 256 * 4);
  bf16*   WBbu = (bf16*)alloc((size_t)512 * 1024 * 2);
  bf16*   WBy  = (bf16*)alloc((size_t)1024 * 1536 * 2);
  bf16*   WB1  = (bf16*)alloc((size_t)4096 * 1024 * 2);   // W1^T
  bf16*   WB2  = (bf16*)alloc((size_t)1024 * 4096 * 2);   // W2^T
  float2* H    = (float2*)alloc((size_t)B_ * NC * 256 * 8);
  float2* Cr   = (float2*)alloc((size_t)B_ * NC * 256 * 8);
  bf16*   Ybf  = (bf16*)alloc((size_t)BL * 1024 * 2);
  bf16*   XS   = (bf16*)alloc((size_t)BL * 1536 * 2);     // [Sr|Si|x]
  bf16*   Bu   = (bf16*)alloc((size_t)BL * 512 * 2);
  // gelu buffer (8192x4096 bf16 = 64 MB) aliases XS+Bu (dead by MLP time)
  bf16*   Hbf  = XS;

  float* out = (float*)d_out;
  float* st  = out + (size_t)BL * DM;

  phaseA<<<1, 256, 0, stream>>>(nu_log, th_log, scal);
  prep_bu<<<512 * 1024 / 256, 256, 0, stream>>>(B_re, B_im, scal, WBbu);
  prep_y<<<1024 * 1536 / 256, 256, 0, stream>>>(C_re, C_im, D_mat, WBy);
  transpose_to_bf16<<<dim3(4096 / 32, 1024 / 32), dim3(32, 8), 0, stream>>>(W1, WB1, 1024, 4096);
  transpose_to_bf16<<<dim3(1024 / 32, 4096 / 32), dim3(32, 8), 0, stream>>>(W2, WB2, 4096, 1024);
  conv_x<<<BL * 256 / 256, 256, 0, stream>>>((const float4*)x, XS);

  // Bu = x @ [gammaB]^T  (M=16384, N=512, K=1024): 64x2 tiles of 256^2
  gemm256<0><<<64 * 2, 512, 0, stream>>>(
      XS + 512, 1536, WBbu, 1024, Bu, 512, 16, 64, 2, nullptr, nullptr);

  scan_pass1<<<B_ * NC, 256, 0, stream>>>(Bu, scal, H);
  scan_pass2<<<B_, 256, 0, stream>>>(H, scal, Cr);
  scan_pass3<<<B_ * NC, 256, 0, stream>>>(Bu, scal, Cr, XS, st);

  // y = [Sr|Si|x] @ [C_re|-C_im|D]^T  (M=16384, N=1024, K=1536): 64x4 tiles
  gemm256<0><<<64 * 4, 512, 0, stream>>>(
      XS, 1536, WBy, 1536, Ybf, 1024, 24, 64, 4, nullptr, nullptr);

  // MLP, M-chunked by 8192 rows (2 chunks)
  for (int i = 0; i < 2; i++) {
    const bf16* Yc = Ybf + (size_t)i * 8192 * 1024;
    float* Oc = out + (size_t)i * 8192 * 1024;
    const float* Xc = x + (size_t)i * 8192 * 1024;
    gemm256<1><<<32 * 16, 512, 0, stream>>>(
        Yc, 1024, WB1, 1024, Hbf, 4096, 16, 32, 16, nullptr, nullptr);
    gemm256<2><<<32 * 4, 512, 0, stream>>>(
        Hbf, 4096, WB2, 4096, Oc, 1024, 64, 32, 4, Xc, reslog);
  }
}

// Round 3
// 610.698 us; speedup vs baseline: 1.1839x; 1.1839x over previous
//
#include <hip/hip_runtime.h>
#include <stdint.h>

typedef __bf16 bf16;
typedef bf16 bf16x8 __attribute__((ext_vector_type(8)));
typedef float f32x4 __attribute__((ext_vector_type(4)));

#define B_  4
#define L_  4096
#define DM  1024
#define DS  256
#define DH  4096
#define BL  16384   // B_*L_
#define CL  64      // scan chunk length
#define NC  64      // chunks per sequence

__device__ __forceinline__ float bfbits(uint32_t lo16) {
  union { uint32_t u; float f; } v; v.u = lo16 << 16; return v.f;
}

__device__ __forceinline__ void async16(const bf16* g, bf16* l) {
  __builtin_amdgcn_global_load_lds(
      (const __attribute__((address_space(1))) uint32_t*)g,
      (__attribute__((address_space(3))) uint32_t*)l, 16, 0, 0);
}

#define SYNC_PRE()  do { asm volatile("" ::: "memory"); __builtin_amdgcn_s_barrier(); } while (0)
#define SYNC_POST() do { __builtin_amdgcn_s_barrier(); asm volatile("" ::: "memory"); } while (0)
#define LGKM0()     asm volatile("s_waitcnt lgkmcnt(0)" ::: "memory")

// ---------------- Phase A ----------------
__global__ void phaseA(const float* __restrict__ nu_log,
                       const float* __restrict__ th_log,
                       float* __restrict__ scal) {
  int n = threadIdx.x;
  float nu = __expf(nu_log[n]);
  float th = __expf(th_log[n]);
  float mod = __expf(-nu);
  float lr = mod * cosf(th);
  float li = mod * sinf(th);
  float g = sqrtf(fmaxf(1.0f - mod * mod, 0.0f));
  float pr = 1.f, pi = 0.f;
  for (int i = 0; i < CL; i++) {
    float nr = pr * lr - pi * li;
    float ni = pr * li + pi * lr;
    pr = nr; pi = ni;
  }
  scal[n] = lr; scal[256 + n] = li;
  scal[512 + n] = pr; scal[768 + n] = pi;
  scal[1024 + n] = g;
}

// ---------------- Weight prep ----------------
__global__ void prep_bu(const float* __restrict__ B_re, const float* __restrict__ B_im,
                        const float* __restrict__ scal, bf16* __restrict__ WB) {
  size_t i = (size_t)blockIdx.x * 256 + threadIdx.x;   // over 512*1024
  int row = (int)(i >> 10), col = (int)(i & 1023);
  int n = row >> 1;
  const float* src = (row & 1) ? B_im : B_re;
  WB[i] = (bf16)(scal[1024 + n] * src[n * 1024 + col]);
}

__global__ void prep_y(const float* __restrict__ C_re, const float* __restrict__ C_im,
                       const float* __restrict__ D_mat, bf16* __restrict__ WB) {
  size_t i = (size_t)blockIdx.x * 256 + threadIdx.x;   // over 1024*1536
  int m = (int)(i / 1536), c = (int)(i % 1536);
  float v;
  if (c < 256)       v = C_re[m * 256 + c];
  else if (c < 512)  v = -C_im[m * 256 + (c - 256)];
  else               v = D_mat[m * 1024 + (c - 512)];
  WB[i] = (bf16)v;
}

__global__ void transpose_to_bf16(const float* __restrict__ in, bf16* __restrict__ out,
                                  int R, int C) {
  __shared__ float tile[32][33];
  int c0 = blockIdx.x * 32, r0 = blockIdx.y * 32;
  int tx = threadIdx.x, ty = threadIdx.y;
  for (int i = 0; i < 32; i += 8)
    tile[ty + i][tx] = in[(size_t)(r0 + ty + i) * C + c0 + tx];
  __syncthreads();
  for (int i = 0; i < 32; i += 8)
    out[(size_t)(c0 + ty + i) * R + r0 + tx] = (bf16)tile[tx][ty + i];
}

__global__ void conv_x(const float4* __restrict__ x, bf16* __restrict__ XS) {
  size_t i = (size_t)blockIdx.x * 256 + threadIdx.x;  // float4 index
  size_t t = i >> 8;
  int d4 = (int)(i & 255);
  float4 v = x[i];
  bf16* o = XS + t * 1536 + 512 + (size_t)d4 * 4;
  o[0] = (bf16)v.x; o[1] = (bf16)v.y; o[2] = (bf16)v.z; o[3] = (bf16)v.w;
}

// Shared epilogue. EPI: 0 = bf16 store, 1 = gelu->bf16, 2 = xres + sig*acc (f32)
template <int EPI>
__device__ __forceinline__ void epi_store(void* C, int ldc, size_t row, size_t col,
                                          float v, float sig, const float* xres) {
  size_t off = row * (size_t)ldc + col;
  if (EPI == 0) {
    ((bf16*)C)[off] = (bf16)v;
  } else if (EPI == 1) {
    float z = 0.7978845608f * (v + 0.044715f * v * v * v);
    float gv = v / (1.f + __expf(-2.f * z));   // v*0.5*(1+tanh(z))
    ((bf16*)C)[off] = (bf16)gv;
  } else {
    ((float*)C)[off] = xres[off] + sig * v;
  }
}

// ---------------- GEMM 256x256: C[m,n] = sum_k A[m,k] * Bt[n,k] -------------
// BK=64, 8 waves (2M x 4N), per-wave 128x64 (8x4 mfma 16x16x32).
// K-MAJOR 4-phase schedule (reads balanced 8/8/4/4):
//   p0: read a[0-3]k0 + b[0-3]k0, stage A(t+1,0) | MFMA m0-3 x n0-3 x k0
//   p1: read a[0-3]k1 + b[0-3]k1, stage A(t+1,1) | MFMA m0-3 k1
//   p2: read a[4-7]k0,            stage B(t+2,0) | MFMA m4-7 k0
//   p3: read a[4-7]k1,            stage B(t+2,1), vmcnt(4) | MFMA m4-7 k1
// Hazards: A(t+1) -> other dbuf (safe). B(t+2) -> current dbuf, but B region
// last READ at p1 whose reads are complete before p1's end barrier -> stages
// at slots 2/3 are safe. vmcnt(4) keeps B(t+2) in flight, drains A(t+1)+older.
// LDS swizzle (per 128x64 half-tile): phys col = c ^ ((row & 12) << 2),
// applied to the GLOBAL source (linear LDS dest) and every ds_read offset.
// XOR must wrap the FULL column offset incl. the +32 k1 shift.
template <int EPI>
__global__ __launch_bounds__(512, 2) void gemm256(
    const bf16* __restrict__ A, int lda,
    const bf16* __restrict__ Bt, int ldb,
    void* __restrict__ C, int ldc, int NK, int mt, int nt,
    const float* __restrict__ xres, const float* __restrict__ reslog) {
  __shared__ __align__(16) bf16 sA[2 * 2 * 8192];   // 64 KB
  __shared__ __align__(16) bf16 sB[2 * 2 * 8192];   // 64 KB

  const int tid  = threadIdx.x;
  const int lane = tid & 63;
  const int wave = tid >> 6;
  const int q = lane >> 4, l16 = lane & 15;
  const int wr = wave >> 2, wc = wave & 3;   // 2 x 4 wave grid

  // XCD tile swizzle (nb % 8 == 0, mt % 8 == 0 for all our shapes)
  int nb = mt * nt;
  int per = nb >> 3;
  int t0 = (blockIdx.x & 7) * per + (blockIdx.x >> 3);
  int gsz = nt << 3;
  int g = t0 / gsz, r = t0 % gsz;
  size_t m0 = (size_t)(g * 8 + (r & 7)) * 256;
  size_t n0 = (size_t)(r >> 3) * 256;

  // staging: thread covers linear LDS bytes tid*16 (+8192B) of a half-tile;
  // source col is pre-swizzled (involution).
  const int srow = tid >> 3;                                   // 0..63
  const int scol = ((tid & 7) << 3) ^ ((srow & 12) << 2);
  const bf16* gA = A  + (m0 + srow) * (size_t)lda + scol;
  const bf16* gB = Bt + (n0 + srow) * (size_t)ldb + scol;
  bf16* lA = sA + tid * 8;
  bf16* lB = sB + tid * 8;

  auto stageA = [&](int kt, int w) {
    const bf16* s = gA + (size_t)(w * 128) * lda + kt * 64;
    bf16* l = lA + ((kt & 1) * 16384 + w * 8192);
    async16(s, l);
    async16(s + (size_t)64 * lda, l + 4096);
  };
  auto stageB = [&](int kt, int w) {
    const bf16* s = gB + (size_t)(w * 128) * ldb + kt * 64;
    bf16* l = lB + ((kt & 1) * 16384 + w * 8192);
    async16(s, l);
    async16(s + (size_t)64 * ldb, l + 4096);
  };

  // prologue: A(0), B(0), B(1);  vmcnt(4) -> A(0),B(0) landed, B(1) in flight
  stageA(0, 0); stageA(0, 1); stageB(0, 0); stageB(0, 1);
  stageB(1, 0); stageB(1, 1);
  __builtin_amdgcn_s_waitcnt(0x0F74);
  __builtin_amdgcn_s_barrier();
  asm volatile("" ::: "memory");

  const int sw  = (l16 & 12) << 2;
  const int qx0 = (q << 3) ^ sw;
  const int qx1 = ((q << 3) + 32) ^ sw;
  const bf16* Ard = sA + wr * 8192 + l16 * 64;
  const bf16* Brd = sB + (wc >> 1) * 8192 + ((wc & 1) * 64 + l16) * 64;

  f32x4 acc[8][4] = {};
  bf16x8 a[4][2], b[4][2];

  for (int t = 0; t < NK; ++t) {
    const int d = (t & 1) * 16384;
    const bf16* Ab = Ard + d;
    const bf16* Bb = Brd + d;

    // ---- p0: k0, m0-3 ----
#pragma unroll
    for (int j = 0; j < 4; ++j) a[j][0] = *(const bf16x8*)&Ab[j * 1024 + qx0];
#pragma unroll
    for (int n = 0; n < 4; ++n) b[n][0] = *(const bf16x8*)&Bb[n * 1024 + qx0];
    if (t + 1 < NK) stageA(t + 1, 0);
    SYNC_PRE(); LGKM0();
    __builtin_amdgcn_s_setprio(1);
#pragma unroll
    for (int j = 0; j < 4; ++j)
#pragma unroll
      for (int n = 0; n < 4; ++n)
        acc[j][n] = __builtin_amdgcn_mfma_f32_16x16x32_bf16(a[j][0], b[n][0], acc[j][n], 0, 0, 0);
    __builtin_amdgcn_s_setprio(0);
    SYNC_POST();

    // ---- p1: k1, m0-3 ----
#pragma unroll
    for (int j = 0; j < 4; ++j) a[j][1] = *(const bf16x8*)&Ab[j * 1024 + qx1];
#pragma unroll
    for (int n = 0; n < 4; ++n) b[n][1] = *(const bf16x8*)&Bb[n * 1024 + qx1];
    if (t + 1 < NK) stageA(t + 1, 1);
    SYNC_PRE(); LGKM0();
    __builtin_amdgcn_s_setprio(1);
#pragma unroll
    for (int j = 0; j < 4; ++j)
#pragma unroll
      for (int n = 0; n < 4; ++n)
        acc[j][n] = __builtin_amdgcn_mfma_f32_16x16x32_bf16(a[j][1], b[n][1], acc[j][n], 0, 0, 0);
    __builtin_amdgcn_s_setprio(0);
    SYNC_POST();

    // ---- p2: k0, m4-7 ----
#pragma unroll
    for (int j = 0; j < 4; ++j) a[j][0] = *(const bf16x8*)&Ab[(4 + j) * 1024 + qx0];
    if (t + 2 < NK) stageB(t + 2, 0);
    SYNC_PRE(); LGKM0();
    __builtin_amdgcn_s_setprio(1);
#pragma unroll
    for (int j = 0; j < 4; ++j)
#pragma unroll
      for (int n = 0; n < 4; ++n)
        acc[4 + j][n] = __builtin_amdgcn_mfma_f32_16x16x32_bf16(a[j][0], b[n][0], acc[4 + j][n], 0, 0, 0);
    __builtin_amdgcn_s_setprio(0);
    SYNC_POST();

    // ---- p3: k1, m4-7; K-tile boundary vmcnt ----
#pragma unroll
    for (int j = 0; j < 4; ++j) a[j][1] = *(const bf16x8*)&Ab[(4 + j) * 1024 + qx1];
    if (t + 2 < NK) {
      stageB(t + 2, 1);
      __builtin_amdgcn_s_waitcnt(0x0F74);   // vmcnt(4): keep B(t+2)
    } else if (t + 1 < NK) {
      __builtin_amdgcn_s_waitcnt(0x0F70);   // vmcnt(0): drain A(NK-1)
    }
    SYNC_PRE(); LGKM0();
    __builtin_amdgcn_s_setprio(1);
#pragma unroll
    for (int j = 0; j < 4; ++j)
#pragma unroll
      for (int n = 0; n < 4; ++n)
        acc[4 + j][n] = __builtin_amdgcn_mfma_f32_16x16x32_bf16(a[j][1], b[n][1], acc[4 + j][n], 0, 0, 0);
    __builtin_amdgcn_s_setprio(0);
    SYNC_POST();
  }

  float sig = 0.f;
  if (EPI == 2) sig = 1.f / (1.f + __expf(-reslog[0]));
#pragma unroll
  for (int mi = 0; mi < 8; ++mi)
#pragma unroll
    for (int ni = 0; ni < 4; ++ni) {
      size_t col = n0 + wc * 64 + ni * 16 + l16;
#pragma unroll
      for (int r2 = 0; r2 < 4; ++r2) {
        size_t row = m0 + wr * 128 + mi * 16 + q * 4 + r2;
        epi_store<EPI>(C, ldc, row, col, acc[mi][ni][r2], sig, xres);
      }
    }
}

// ---------------- GEMM 128x256 (for small-M-tile / wide-grid shapes) --------
// BK=64, 8 waves (2M x 4N), per-wave 64x64 (4x4 mfma). 2-phase k-major:
//   p0: read a[0-3]k0 + b[0-3]k0, stage A(t+1)            | 16 MFMA k0
//   p1: read a[0-3]k1 + b[0-3]k1, stage B(t+2,0/1), vmcnt | 16 MFMA k1
// A double-buffered (t&1); B TRIPLE-buffered (t%3): stage distance 2 with
// 2 bufs would overwrite the region other waves are still reading in p1.
// LDS = 2*16KB (A) + 3*32KB (B) = 128 KB. Same swizzle as gemm256.
template <int EPI>
__global__ __launch_bounds__(512, 2) void gemm128(
    const bf16* __restrict__ A, int lda,
    const bf16* __restrict__ Bt, int ldb,
    void* __restrict__ C, int ldc, int NK, int mt, int nt,
    const float* __restrict__ xres, const float* __restrict__ reslog) {
  __shared__ __align__(16) bf16 sA[2 * 8192];    // 32 KB
  __shared__ __align__(16) bf16 sB[3 * 16384];   // 96 KB

  const int tid  = threadIdx.x;
  const int lane = tid & 63;
  const int wave = tid >> 6;
  const int q = lane >> 4, l16 = lane & 15;
  const int wr = wave >> 2, wc = wave & 3;

  int nb = mt * nt;
  int per = nb >> 3;
  int t0 = (blockIdx.x & 7) * per + (blockIdx.x >> 3);
  int gsz = nt << 3;
  int g = t0 / gsz, r = t0 % gsz;
  size_t m0 = (size_t)(g * 8 + (r & 7)) * 128;
  size_t n0 = (size_t)(r >> 3) * 256;

  const int srow = tid >> 3;
  const int scol = ((tid & 7) << 3) ^ ((srow & 12) << 2);
  const bf16* gA = A  + (m0 + srow) * (size_t)lda + scol;
  const bf16* gB = Bt + (n0 + srow) * (size_t)ldb + scol;
  bf16* lA = sA + tid * 8;
  bf16* lB = sB + tid * 8;

  auto stageA = [&](int kt) {          // whole 128x64 A tile
    const bf16* s = gA + kt * 64;
    bf16* l = lA + (kt & 1) * 8192;
    async16(s, l);
    async16(s + (size_t)64 * lda, l + 4096);
  };
  auto stageB = [&](int kt, int w) {   // B half-tile w: n in [w*128,(w+1)*128)
    const bf16* s = gB + (size_t)(w * 128) * ldb + kt * 64;
    bf16* l = lB + ((kt % 3) * 16384 + w * 8192);
    async16(s, l);
    async16(s + (size_t)64 * ldb, l + 4096);
  };

  // prologue: A(0), B(0), B(1); vmcnt(4) -> A(0),B(0) landed, B(1) in flight
  stageA(0); stageB(0, 0); stageB(0, 1);
  stageB(1, 0); stageB(1, 1);
  __builtin_amdgcn_s_waitcnt(0x0F74);
  __builtin_amdgcn_s_barrier();
  asm volatile("" ::: "memory");

  const int sw  = (l16 & 12) << 2;
  const int qx0 = (q << 3) ^ sw;
  const int qx1 = ((q << 3) + 32) ^ sw;
  const bf16* Ard = sA + (wr * 64 + l16) * 64;
  const bf16* Brd = sB + (wc >> 1) * 8192 + ((wc & 1) * 64 + l16) * 64;

  f32x4 acc[4][4] = {};
  bf16x8 a[4][2], b[4][2];

  for (int t = 0; t < NK; ++t) {
    const bf16* Ab = Ard + (t & 1) * 8192;
    const bf16* Bb = Brd + (t % 3) * 16384;

    // ---- p0: k0 ----
#pragma unroll
    for (int j = 0; j < 4; ++j) a[j][0] = *(const bf16x8*)&Ab[j * 1024 + qx0];
#pragma unroll
    for (int n = 0; n < 4; ++n) b[n][0] = *(const bf16x8*)&Bb[n * 1024 + qx0];
    if (t + 1 < NK) stageA(t + 1);
    SYNC_PRE(); LGKM0();
    __builtin_amdgcn_s_setprio(1);
#pragma unroll
    for (int j = 0; j < 4; ++j)
#pragma unroll
      for (int n = 0; n < 4; ++n)
        acc[j][n] = __builtin_amdgcn_mfma_f32_16x16x32_bf16(a[j][0], b[n][0], acc[j][n], 0, 0, 0);
    __builtin_amdgcn_s_setprio(0);
    SYNC_POST();

    // ---- p1: k1; stage B(t+2) both halves; vmcnt ----
#pragma unroll
    for (int j = 0; j < 4; ++j) a[j][1] = *(const bf16x8*)&Ab[j * 1024 + qx1];
#pragma unroll
    for (int n = 0; n < 4; ++n) b[n][1] = *(const bf16x8*)&Bb[n * 1024 + qx1];
    if (t + 2 < NK) {
      stageB(t + 2, 0); stageB(t + 2, 1);
      __builtin_amdgcn_s_waitcnt(0x0F74);   // vmcnt(4): keep B(t+2)
    } else if (t + 1 < NK) {
      __builtin_amdgcn_s_waitcnt(0x0F70);   // vmcnt(0): drain A(NK-1)
    }
    SYNC_PRE(); LGKM0();
    __builtin_amdgcn_s_setprio(1);
#pragma unroll
    for (int j = 0; j < 4; ++j)
#pragma unroll
      for (int n = 0; n < 4; ++n)
        acc[j][n] = __builtin_amdgcn_mfma_f32_16x16x32_bf16(a[j][1], b[n][1], acc[j][n], 0, 0, 0);
    __builtin_amdgcn_s_setprio(0);
    SYNC_POST();
  }

  float sig = 0.f;
  if (EPI == 2) sig = 1.f / (1.f + __expf(-reslog[0]));
#pragma unroll
  for (int mi = 0; mi < 4; ++mi)
#pragma unroll
    for (int ni = 0; ni < 4; ++ni) {
      size_t col = n0 + wc * 64 + ni * 16 + l16;
#pragma unroll
      for (int r2 = 0; r2 < 4; ++r2) {
        size_t row = m0 + wr * 64 + mi * 16 + q * 4 + r2;
        epi_store<EPI>(C, ldc, row, col, acc[mi][ni][r2], sig, xres);
      }
    }
}

// ---------------- Scan ----------------
__global__ void scan_pass1(const bf16* __restrict__ Bu, const float* __restrict__ scal,
                           float2* __restrict__ H) {
  int b = blockIdx.x >> 6, c = blockIdx.x & 63, n = threadIdx.x;
  float lr = scal[n], li = scal[256 + n];
  float sr = 0.f, si = 0.f;
  size_t t0 = (size_t)b * L_ + (size_t)c * CL;
  const uint32_t* p = (const uint32_t*)(Bu + t0 * 512) + n;
  for (int j = 0; j < CL; j++) {
    uint32_t u = p[(size_t)j * 256];
    float ur = bfbits(u & 0xffffu), ui = bfbits(u >> 16);
    float nr = lr * sr - li * si + ur;
    float ni = lr * si + li * sr + ui;
    sr = nr; si = ni;
  }
  H[(size_t)(b * NC + c) * 256 + n] = make_float2(sr, si);
}

__global__ void scan_pass2(const float2* __restrict__ H, const float* __restrict__ scal,
                           float2* __restrict__ Carry) {
  int b = blockIdx.x, n = threadIdx.x;
  float Pr = scal[512 + n], Pi = scal[768 + n];
  float cr = 0.f, ci = 0.f;
  for (int c = 0; c < NC; c++) {
    Carry[(size_t)(b * NC + c) * 256 + n] = make_float2(cr, ci);
    float2 h = H[(size_t)(b * NC + c) * 256 + n];
    float nr = Pr * cr - Pi * ci + h.x;
    float ni = Pr * ci + Pi * cr + h.y;
    cr = nr; ci = ni;
  }
}

// st layout: PLANAR-GLOBAL — st[0..1023] = re (b-major), st[1024..2047] = im
__global__ void scan_pass3(const bf16* __restrict__ Bu, const float* __restrict__ scal,
                           const float2* __restrict__ Carry, bf16* __restrict__ XS,
                           float* __restrict__ st) {
  int b = blockIdx.x >> 6, c = blockIdx.x & 63, n = threadIdx.x;
  float lr = scal[n], li = scal[256 + n];
  float2 cv = Carry[(size_t)(b * NC + c) * 256 + n];
  float sr = cv.x, si = cv.y;
  size_t t0 = (size_t)b * L_ + (size_t)c * CL;
  const uint32_t* p = (const uint32_t*)(Bu + t0 * 512) + n;
  bf16* qp = XS + t0 * 1536 + n;
  for (int j = 0; j < CL; j++) {
    uint32_t u = p[(size_t)j * 256];
    float ur = bfbits(u & 0xffffu), ui = bfbits(u >> 16);
    float nr = lr * sr - li * si + ur;
    float ni = lr * si + li * sr + ui;
    sr = nr; si = ni;
    qp[(size_t)j * 1536] = (bf16)sr;
    qp[(size_t)j * 1536 + 256] = (bf16)si;
  }
  if (c == NC - 1) {
    st[(size_t)b * 256 + n] = sr;
    st[1024 + (size_t)b * 256 + n] = si;
  }
}

// ---------------- Launch ----------------
extern "C" void kernel_launch(void* const* d_in, const int* in_sizes, int n_in,
                              void* d_out, int out_size, void* d_ws, size_t ws_size,
                              hipStream_t stream) {
  const float* x      = (const float*)d_in[0];
  const float* nu_log = (const float*)d_in[1];
  const float* th_log = (const float*)d_in[2];
  const float* B_re   = (const float*)d_in[3];
  const float* B_im   = (const float*)d_in[4];
  const float* C_re   = (const float*)d_in[5];
  const float* C_im   = (const float*)d_in[6];
  const float* D_mat  = (const float*)d_in[7];
  const float* W1     = (const float*)d_in[8];
  const float* W2     = (const float*)d_in[9];
  const float* reslog = (const float*)d_in[10];

  char* wsb = (char*)d_ws;
  size_t off = 0;
  auto alloc = [&](size_t bytes) {
    void* p = wsb + off;
    off += (bytes + 255) & ~(size_t)255;
    return p;
  };
  float*  scal = (float*)alloc(5 * 256 * 4);
  bf16*   WBbu = (bf16*)alloc((size_t)512 * 1024 * 2);
  bf16*   WBy  = (bf16*)alloc((size_t)1024 * 1536 * 2);
  bf16*   WB1  = (bf16*)alloc((size_t)4096 * 1024 * 2);   // W1^T
  bf16*   WB2  = (bf16*)alloc((size_t)1024 * 4096 * 2);   // W2^T
  float2* H    = (float2*)alloc((size_t)B_ * NC * 256 * 8);
  float2* Cr   = (float2*)alloc((size_t)B_ * NC * 256 * 8);
  bf16*   Ybf  = (bf16*)alloc((size_t)BL * 1024 * 2);
  bf16*   XS   = (bf16*)alloc((size_t)BL * 1536 * 2);     // [Sr|Si|x]
  bf16*   Bu   = (bf16*)alloc((size_t)BL * 512 * 2);
  // gelu buffer (8192x4096 bf16 = 64 MB) aliases XS+Bu (dead by MLP time)
  bf16*   Hbf  = XS;

  float* out = (float*)d_out;
  float* st  = out + (size_t)BL * DM;

  phaseA<<<1, 256, 0, stream>>>(nu_log, th_log, scal);
  prep_bu<<<512 * 1024 / 256, 256, 0, stream>>>(B_re, B_im, scal, WBbu);
  prep_y<<<1024 * 1536 / 256, 256, 0, stream>>>(C_re, C_im, D_mat, WBy);
  transpose_to_bf16<<<dim3(4096 / 32, 1024 / 32), dim3(32, 8), 0, stream>>>(W1, WB1, 1024, 4096);
  transpose_to_bf16<<<dim3(1024 / 32, 4096 / 32), dim3(32, 8), 0, stream>>>(W2, WB2, 4096, 1024);
  conv_x<<<BL * 256 / 256, 256, 0, stream>>>((const float4*)x, XS);

  // Bu = x @ [gammaB]^T  (M=16384, N=512, K=1024): 128x256 tiles -> 256 blocks
  gemm128<0><<<128 * 2, 512, 0, stream>>>(
      XS + 512, 1536, WBbu, 1024, Bu, 512, 16, 128, 2, nullptr, nullptr);

  scan_pass1<<<B_ * NC, 256, 0, stream>>>(Bu, scal, H);
  scan_pass2<<<B_, 256, 0, stream>>>(H, scal, Cr);
  scan_pass3<<<B_ * NC, 256, 0, stream>>>(Bu, scal, Cr, XS, st);

  // y = [Sr|Si|x] @ [C_re|-C_im|D]^T  (M=16384, N=1024, K=1536): 256^2, 256 blk
  gemm256<0><<<64 * 4, 512, 0, stream>>>(
      XS, 1536, WBy, 1536, Ybf, 1024, 24, 64, 4, nullptr, nullptr);

  // MLP, M-chunked by 8192 rows (2 chunks)
  for (int i = 0; i < 2; i++) {
    const bf16* Yc = Ybf + (size_t)i * 8192 * 1024;
    float* Oc = out + (size_t)i * 8192 * 1024;
    const float* Xc = x + (size_t)i * 8192 * 1024;
    // MLP1: M=8192, N=4096, K=1024 -> 256^2, 512 blocks (2 rounds)
    gemm256<1><<<32 * 16, 512, 0, stream>>>(
        Yc, 1024, WB1, 1024, Hbf, 4096, 16, 32, 16, nullptr, nullptr);
    // MLP2: M=8192, N=1024, K=4096 -> 128x256 tiles, 256 blocks (full GPU)
    gemm128<2><<<64 * 4, 512, 0, stream>>>(
        Hbf, 4096, WB2, 4096, Oc, 1024, 64, 64, 4, Xc, reslog);
  }
}

// Round 4
// 569.716 us; speedup vs baseline: 1.2690x; 1.0719x over previous
//
#include <hip/hip_runtime.h>
#include <stdint.h>

typedef __bf16 bf16;
typedef bf16 bf16x8 __attribute__((ext_vector_type(8)));
typedef float f32x4 __attribute__((ext_vector_type(4)));

#define B_  4
#define L_  4096
#define DM  1024
#define DS  256
#define DH  4096
#define BL  16384   // B_*L_
#define CL  64      // scan chunk length
#define NC  64      // chunks per sequence

__device__ __forceinline__ float bfbits(uint32_t lo16) {
  union { uint32_t u; float f; } v; v.u = lo16 << 16; return v.f;
}

__device__ __forceinline__ void async16(const bf16* g, bf16* l) {
  __builtin_amdgcn_global_load_lds(
      (const __attribute__((address_space(1))) uint32_t*)g,
      (__attribute__((address_space(3))) uint32_t*)l, 16, 0, 0);
}

#define MEMFENCE() asm volatile("" ::: "memory")

// ---------------- Phase A ----------------
__global__ void phaseA(const float* __restrict__ nu_log,
                       const float* __restrict__ th_log,
                       float* __restrict__ scal) {
  int n = threadIdx.x;
  float nu = __expf(nu_log[n]);
  float th = __expf(th_log[n]);
  float mod = __expf(-nu);
  float lr = mod * cosf(th);
  float li = mod * sinf(th);
  float g = sqrtf(fmaxf(1.0f - mod * mod, 0.0f));
  float pr = 1.f, pi = 0.f;
  for (int i = 0; i < CL; i++) {
    float nr = pr * lr - pi * li;
    float ni = pr * li + pi * lr;
    pr = nr; pi = ni;
  }
  scal[n] = lr; scal[256 + n] = li;
  scal[512 + n] = pr; scal[768 + n] = pi;
  scal[1024 + n] = g;
}

// ---------------- Weight prep ----------------
__global__ void prep_bu(const float* __restrict__ B_re, const float* __restrict__ B_im,
                        const float* __restrict__ scal, bf16* __restrict__ WB) {
  size_t i = (size_t)blockIdx.x * 256 + threadIdx.x;   // over 512*1024
  int row = (int)(i >> 10), col = (int)(i & 1023);
  int n = row >> 1;
  const float* src = (row & 1) ? B_im : B_re;
  WB[i] = (bf16)(scal[1024 + n] * src[n * 1024 + col]);
}

__global__ void prep_y(const float* __restrict__ C_re, const float* __restrict__ C_im,
                       const float* __restrict__ D_mat, bf16* __restrict__ WB) {
  size_t i = (size_t)blockIdx.x * 256 + threadIdx.x;   // over 1024*1536
  int m = (int)(i / 1536), c = (int)(i % 1536);
  float v;
  if (c < 256)       v = C_re[m * 256 + c];
  else if (c < 512)  v = -C_im[m * 256 + (c - 256)];
  else               v = D_mat[m * 1024 + (c - 512)];
  WB[i] = (bf16)v;
}

__global__ void transpose_to_bf16(const float* __restrict__ in, bf16* __restrict__ out,
                                  int R, int C) {
  __shared__ float tile[32][33];
  int c0 = blockIdx.x * 32, r0 = blockIdx.y * 32;
  int tx = threadIdx.x, ty = threadIdx.y;
  for (int i = 0; i < 32; i += 8)
    tile[ty + i][tx] = in[(size_t)(r0 + ty + i) * C + c0 + tx];
  __syncthreads();
  for (int i = 0; i < 32; i += 8)
    out[(size_t)(c0 + ty + i) * R + r0 + tx] = (bf16)tile[tx][ty + i];
}

__global__ void conv_x(const float4* __restrict__ x, bf16* __restrict__ XS) {
  size_t i = (size_t)blockIdx.x * 256 + threadIdx.x;  // float4 index
  size_t t = i >> 8;
  int d4 = (int)(i & 255);
  float4 v = x[i];
  bf16* o = XS + t * 1536 + 512 + (size_t)d4 * 4;
  o[0] = (bf16)v.x; o[1] = (bf16)v.y; o[2] = (bf16)v.z; o[3] = (bf16)v.w;
}

// Shared epilogue. EPI: 0 = bf16 store, 1 = gelu->bf16, 2 = xres + sig*acc (f32)
template <int EPI>
__device__ __forceinline__ void epi_store(void* C, int ldc, size_t row, size_t col,
                                          float v, float sig, const float* xres) {
  size_t off = row * (size_t)ldc + col;
  if (EPI == 0) {
    ((bf16*)C)[off] = (bf16)v;
  } else if (EPI == 1) {
    float z = 0.7978845608f * (v + 0.044715f * v * v * v);
    float gv = v / (1.f + __expf(-2.f * z));   // v*0.5*(1+tanh(z))
    ((bf16*)C)[off] = (bf16)gv;
  } else {
    ((float*)C)[off] = xres[off] + sig * v;
  }
}

// ---------------- GEMM 256x256: C[m,n] = sum_k A[m,k] * Bt[n,k] -------------
// BK=64, 8 waves (2M x 4N), per-wave 128x64 (8x4 mfma 16x16x32).
// SINGLE-BARRIER K-tile schedule (LDS reads overlap MFMA drain; compiler
// inserts counted lgkmcnt between ds_read and consuming MFMA):
//   tile t: {read aLo/b (16x b128) | DMA A(t+1),B(t+1) -> other dbuf (8 ops) |
//            MFMA k0,k1 m0-3 | read aHi (8) | MFMA k0,k1 m4-7 |
//            vmcnt(0) (free: ~1 tile in flight) | s_barrier}
// Hazards: reads(t) all drain (lgkm) before each wave's last cluster -> before
// barrier -> DMA(t+1) into other dbuf never races a read. DMA(t+1) certified
// by vmcnt(0)+barrier before tile t+1's reads.
// LDS swizzle (per 128x64-elem half-tile): elem (r,c) stored at phys col
// c ^ ((r&7)<<3)  [= byte ^ ((r&7)<<4)]. Applied on the GLOBAL source during
// staging (LDS dest stays linear, global_load_lds requirement) and on every
// ds_read column. Reads: 8 distinct 16B slots per 8 rows -> only free 2-way
// row-pair aliasing. XOR must wrap the FULL col offset incl. the +32 k1 shift.
template <int EPI>
__global__ __launch_bounds__(512, 2) void gemm256(
    const bf16* __restrict__ A, int lda,
    const bf16* __restrict__ Bt, int ldb,
    void* __restrict__ C, int ldc, int NK, int mt, int nt,
    const float* __restrict__ xres, const float* __restrict__ reslog) {
  __shared__ __align__(16) bf16 sA[2 * 16384];   // [dbuf][2 half][128][64] 64KB
  __shared__ __align__(16) bf16 sB[2 * 16384];   // 64KB

  const int tid  = threadIdx.x;
  const int lane = tid & 63;
  const int wave = tid >> 6;
  const int q = lane >> 4, l16 = lane & 15;
  const int wr = wave >> 2, wc = wave & 3;   // 2 x 4 wave grid

  // XCD tile swizzle (nb % 8 == 0, mt % 8 == 0 for all our shapes)
  int nb = mt * nt;
  int per = nb >> 3;
  int t0 = (blockIdx.x & 7) * per + (blockIdx.x >> 3);
  int gsz = nt << 3;
  int g = t0 / gsz, r = t0 % gsz;
  size_t m0 = (size_t)(g * 8 + (r & 7)) * 256;
  size_t n0 = (size_t)(r >> 3) * 256;

  // staging: thread covers linear LDS bytes tid*16 (+8192B) per half-tile;
  // source col is the swizzle-inverse (involution) position.
  const int srow = tid >> 3;                                   // 0..63
  const int scol = (((tid & 7) ^ ((tid >> 3) & 7)) << 3);
  const bf16* gA = A  + (m0 + srow) * (size_t)lda + scol;
  const bf16* gB = Bt + (n0 + srow) * (size_t)ldb + scol;
  bf16* lA = sA + tid * 8;
  bf16* lB = sB + tid * 8;

  auto stageA = [&](int kt) {          // whole 256x64 A tile -> dbuf kt&1
    const bf16* s = gA + kt * 64;
    bf16* l = lA + (kt & 1) * 16384;
    async16(s, l);                              // half0 rows 0-63
    async16(s + (size_t)64  * lda, l + 4096);   // half0 rows 64-127
    async16(s + (size_t)128 * lda, l + 8192);   // half1 rows 128-191
    async16(s + (size_t)192 * lda, l + 12288);  // half1 rows 192-255
  };
  auto stageB = [&](int kt) {
    const bf16* s = gB + kt * 64;
    bf16* l = lB + (kt & 1) * 16384;
    async16(s, l);
    async16(s + (size_t)64  * ldb, l + 4096);
    async16(s + (size_t)128 * ldb, l + 8192);
    async16(s + (size_t)192 * ldb, l + 12288);
  };

  // prologue
  stageA(0); stageB(0);
  __builtin_amdgcn_s_waitcnt(0x0F70);   // vmcnt(0)
  __builtin_amdgcn_s_barrier();
  MEMFENCE();

  const int sw  = (l16 & 7) << 3;
  const int qx0 = (q << 3) ^ sw;
  const int qx1 = ((q << 3) + 32) ^ sw;
  const bf16* Ard = sA + wr * 8192 + l16 * 64;
  const bf16* Brd = sB + (wc >> 1) * 8192 + ((wc & 1) * 64 + l16) * 64;

  f32x4 acc[8][4] = {};
  bf16x8 aL[4][2], aH[4][2], b[4][2];

  for (int t = 0; t < NK; ++t) {
    const int d = (t & 1) * 16384;
    const bf16* Ab = Ard + d;
    const bf16* Bb = Brd + d;

    // reads: aLo + all B (16 x b128)
#pragma unroll
    for (int j = 0; j < 4; ++j) {
      aL[j][0] = *(const bf16x8*)&Ab[j * 1024 + qx0];
      aL[j][1] = *(const bf16x8*)&Ab[j * 1024 + qx1];
    }
#pragma unroll
    for (int n = 0; n < 4; ++n) {
      b[n][0] = *(const bf16x8*)&Bb[n * 1024 + qx0];
      b[n][1] = *(const bf16x8*)&Bb[n * 1024 + qx1];
    }
    // prefetch next K-tile into the other dbuf (8 DMA ops); pin issue early
    if (t + 1 < NK) { stageA(t + 1); stageB(t + 1); }
    MEMFENCE();

    __builtin_amdgcn_s_setprio(1);
#pragma unroll
    for (int j = 0; j < 4; ++j)
#pragma unroll
      for (int n = 0; n < 4; ++n)
        acc[j][n] = __builtin_amdgcn_mfma_f32_16x16x32_bf16(aL[j][0], b[n][0], acc[j][n], 0, 0, 0);
#pragma unroll
    for (int j = 0; j < 4; ++j)
#pragma unroll
      for (int n = 0; n < 4; ++n)
        acc[j][n] = __builtin_amdgcn_mfma_f32_16x16x32_bf16(aL[j][1], b[n][1], acc[j][n], 0, 0, 0);

    // aHi reads (8 x b128) — issued while m0-3 MFMAs drain
#pragma unroll
    for (int j = 0; j < 4; ++j) {
      aH[j][0] = *(const bf16x8*)&Ab[(4 + j) * 1024 + qx0];
      aH[j][1] = *(const bf16x8*)&Ab[(4 + j) * 1024 + qx1];
    }
#pragma unroll
    for (int j = 0; j < 4; ++j)
#pragma unroll
      for (int n = 0; n < 4; ++n)
        acc[4 + j][n] = __builtin_amdgcn_mfma_f32_16x16x32_bf16(aH[j][0], b[n][0], acc[4 + j][n], 0, 0, 0);
#pragma unroll
    for (int j = 0; j < 4; ++j)
#pragma unroll
      for (int n = 0; n < 4; ++n)
        acc[4 + j][n] = __builtin_amdgcn_mfma_f32_16x16x32_bf16(aH[j][1], b[n][1], acc[4 + j][n], 0, 0, 0);
    __builtin_amdgcn_s_setprio(0);

    MEMFENCE();
    __builtin_amdgcn_s_waitcnt(0x0F70);   // vmcnt(0): DMA(t+1) landed (free)
    __builtin_amdgcn_s_barrier();
    MEMFENCE();
  }

  float sig = 0.f;
  if (EPI == 2) sig = 1.f / (1.f + __expf(-reslog[0]));
#pragma unroll
  for (int mi = 0; mi < 8; ++mi)
#pragma unroll
    for (int ni = 0; ni < 4; ++ni) {
      size_t col = n0 + wc * 64 + ni * 16 + l16;
#pragma unroll
      for (int r2 = 0; r2 < 4; ++r2) {
        size_t row = m0 + wr * 128 + mi * 16 + q * 4 + r2;
        epi_store<EPI>(C, ldc, row, col, acc[mi][ni][r2], sig, xres);
      }
    }
}

// ---------------- GEMM 128x256 (wide-grid shapes: Bu, MLP2) -----------------
// Same single-barrier schedule. 8 waves (2M x 4N), wave-tile 64x64.
// LDS: A [dbuf][128][64] 32KB + B [dbuf][2 half][128][64] 64KB = 96KB.
template <int EPI>
__global__ __launch_bounds__(512, 2) void gemm128(
    const bf16* __restrict__ A, int lda,
    const bf16* __restrict__ Bt, int ldb,
    void* __restrict__ C, int ldc, int NK, int mt, int nt,
    const float* __restrict__ xres, const float* __restrict__ reslog) {
  __shared__ __align__(16) bf16 sA[2 * 8192];    // 32 KB
  __shared__ __align__(16) bf16 sB[2 * 16384];   // 64 KB

  const int tid  = threadIdx.x;
  const int lane = tid & 63;
  const int wave = tid >> 6;
  const int q = lane >> 4, l16 = lane & 15;
  const int wr = wave >> 2, wc = wave & 3;

  int nb = mt * nt;
  int per = nb >> 3;
  int t0 = (blockIdx.x & 7) * per + (blockIdx.x >> 3);
  int gsz = nt << 3;
  int g = t0 / gsz, r = t0 % gsz;
  size_t m0 = (size_t)(g * 8 + (r & 7)) * 128;
  size_t n0 = (size_t)(r >> 3) * 256;

  const int srow = tid >> 3;
  const int scol = (((tid & 7) ^ ((tid >> 3) & 7)) << 3);
  const bf16* gA = A  + (m0 + srow) * (size_t)lda + scol;
  const bf16* gB = Bt + (n0 + srow) * (size_t)ldb + scol;
  bf16* lA = sA + tid * 8;
  bf16* lB = sB + tid * 8;

  auto stageA = [&](int kt) {          // 128x64 A tile
    const bf16* s = gA + kt * 64;
    bf16* l = lA + (kt & 1) * 8192;
    async16(s, l);
    async16(s + (size_t)64 * lda, l + 4096);
  };
  auto stageB = [&](int kt) {          // 256x64 B tile (2 half-tiles)
    const bf16* s = gB + kt * 64;
    bf16* l = lB + (kt & 1) * 16384;
    async16(s, l);
    async16(s + (size_t)64  * ldb, l + 4096);
    async16(s + (size_t)128 * ldb, l + 8192);
    async16(s + (size_t)192 * ldb, l + 12288);
  };

  stageA(0); stageB(0);
  __builtin_amdgcn_s_waitcnt(0x0F70);
  __builtin_amdgcn_s_barrier();
  MEMFENCE();

  const int sw  = (l16 & 7) << 3;
  const int qx0 = (q << 3) ^ sw;
  const int qx1 = ((q << 3) + 32) ^ sw;
  const bf16* Ard = sA + (wr * 64 + l16) * 64;
  const bf16* Brd = sB + (wc >> 1) * 8192 + ((wc & 1) * 64 + l16) * 64;

  f32x4 acc[4][4] = {};
  bf16x8 a[4][2], b[4][2];

  for (int t = 0; t < NK; ++t) {
    const bf16* Ab = Ard + (t & 1) * 8192;
    const bf16* Bb = Brd + (t & 1) * 16384;

#pragma unroll
    for (int j = 0; j < 4; ++j) {
      a[j][0] = *(const bf16x8*)&Ab[j * 1024 + qx0];
      a[j][1] = *(const bf16x8*)&Ab[j * 1024 + qx1];
    }
#pragma unroll
    for (int n = 0; n < 4; ++n) {
      b[n][0] = *(const bf16x8*)&Bb[n * 1024 + qx0];
      b[n][1] = *(const bf16x8*)&Bb[n * 1024 + qx1];
    }
    if (t + 1 < NK) { stageA(t + 1); stageB(t + 1); }
    MEMFENCE();

    __builtin_amdgcn_s_setprio(1);
#pragma unroll
    for (int j = 0; j < 4; ++j)
#pragma unroll
      for (int n = 0; n < 4; ++n)
        acc[j][n] = __builtin_amdgcn_mfma_f32_16x16x32_bf16(a[j][0], b[n][0], acc[j][n], 0, 0, 0);
#pragma unroll
    for (int j = 0; j < 4; ++j)
#pragma unroll
      for (int n = 0; n < 4; ++n)
        acc[j][n] = __builtin_amdgcn_mfma_f32_16x16x32_bf16(a[j][1], b[n][1], acc[j][n], 0, 0, 0);
    __builtin_amdgcn_s_setprio(0);

    MEMFENCE();
    __builtin_amdgcn_s_waitcnt(0x0F70);
    __builtin_amdgcn_s_barrier();
    MEMFENCE();
  }

  float sig = 0.f;
  if (EPI == 2) sig = 1.f / (1.f + __expf(-reslog[0]));
#pragma unroll
  for (int mi = 0; mi < 4; ++mi)
#pragma unroll
    for (int ni = 0; ni < 4; ++ni) {
      size_t col = n0 + wc * 64 + ni * 16 + l16;
#pragma unroll
      for (int r2 = 0; r2 < 4; ++r2) {
        size_t row = m0 + wr * 64 + mi * 16 + q * 4 + r2;
        epi_store<EPI>(C, ldc, row, col, acc[mi][ni][r2], sig, xres);
      }
    }
}

// ---------------- Scan ----------------
__global__ void scan_pass1(const bf16* __restrict__ Bu, const float* __restrict__ scal,
                           float2* __restrict__ H) {
  int b = blockIdx.x >> 6, c = blockIdx.x & 63, n = threadIdx.x;
  float lr = scal[n], li = scal[256 + n];
  float sr = 0.f, si = 0.f;
  size_t t0 = (size_t)b * L_ + (size_t)c * CL;
  const uint32_t* p = (const uint32_t*)(Bu + t0 * 512) + n;
  for (int j = 0; j < CL; j++) {
    uint32_t u = p[(size_t)j * 256];
    float ur = bfbits(u & 0xffffu), ui = bfbits(u >> 16);
    float nr = lr * sr - li * si + ur;
    float ni = lr * si + li * sr + ui;
    sr = nr; si = ni;
  }
  H[(size_t)(b * NC + c) * 256 + n] = make_float2(sr, si);
}

__global__ void scan_pass2(const float2* __restrict__ H, const float* __restrict__ scal,
                           float2* __restrict__ Carry) {
  int b = blockIdx.x, n = threadIdx.x;
  float Pr = scal[512 + n], Pi = scal[768 + n];
  float cr = 0.f, ci = 0.f;
  for (int c = 0; c < NC; c++) {
    Carry[(size_t)(b * NC + c) * 256 + n] = make_float2(cr, ci);
    float2 h = H[(size_t)(b * NC + c) * 256 + n];
    float nr = Pr * cr - Pi * ci + h.x;
    float ni = Pr * ci + Pi * cr + h.y;
    cr = nr; ci = ni;
  }
}

// st layout: PLANAR-GLOBAL — st[0..1023] = re (b-major), st[1024..2047] = im
__global__ void scan_pass3(const bf16* __restrict__ Bu, const float* __restrict__ scal,
                           const float2* __restrict__ Carry, bf16* __restrict__ XS,
                           float* __restrict__ st) {
  int b = blockIdx.x >> 6, c = blockIdx.x & 63, n = threadIdx.x;
  float lr = scal[n], li = scal[256 + n];
  float2 cv = Carry[(size_t)(b * NC + c) * 256 + n];
  float sr = cv.x, si = cv.y;
  size_t t0 = (size_t)b * L_ + (size_t)c * CL;
  const uint32_t* p = (const uint32_t*)(Bu + t0 * 512) + n;
  bf16* qp = XS + t0 * 1536 + n;
  for (int j = 0; j < CL; j++) {
    uint32_t u = p[(size_t)j * 256];
    float ur = bfbits(u & 0xffffu), ui = bfbits(u >> 16);
    float nr = lr * sr - li * si + ur;
    float ni = lr * si + li * sr + ui;
    sr = nr; si = ni;
    qp[(size_t)j * 1536] = (bf16)sr;
    qp[(size_t)j * 1536 + 256] = (bf16)si;
  }
  if (c == NC - 1) {
    st[(size_t)b * 256 + n] = sr;
    st[1024 + (size_t)b * 256 + n] = si;
  }
}

// ---------------- Launch ----------------
extern "C" void kernel_launch(void* const* d_in, const int* in_sizes, int n_in,
                              void* d_out, int out_size, void* d_ws, size_t ws_size,
                              hipStream_t stream) {
  const float* x      = (const float*)d_in[0];
  const float* nu_log = (const float*)d_in[1];
  const float* th_log = (const float*)d_in[2];
  const float* B_re   = (const float*)d_in[3];
  const float* B_im   = (const float*)d_in[4];
  const float* C_re   = (const float*)d_in[5];
  const float* C_im   = (const float*)d_in[6];
  const float* D_mat  = (const float*)d_in[7];
  const float* W1     = (const float*)d_in[8];
  const float* W2     = (const float*)d_in[9];
  const float* reslog = (const float*)d_in[10];

  char* wsb = (char*)d_ws;
  size_t off = 0;
  auto alloc = [&](size_t bytes) {
    void* p = wsb + off;
    off += (bytes + 255) & ~(size_t)255;
    return p;
  };
  float*  scal = (float*)alloc(5 * 256 * 4);
  bf16*   WBbu = (bf16*)alloc((size_t)512 * 1024 * 2);
  bf16*   WBy  = (bf16*)alloc((size_t)1024 * 1536 * 2);
  bf16*   WB1  = (bf16*)alloc((size_t)4096 * 1024 * 2);   // W1^T
  bf16*   WB2  = (bf16*)alloc((size_t)1024 * 4096 * 2);   // W2^T
  float2* H    = (float2*)alloc((size_t)B_ * NC * 256 * 8);
  float2* Cr   = (float2*)alloc((size_t)B_ * NC * 256 * 8);
  bf16*   Ybf  = (bf16*)alloc((size_t)BL * 1024 * 2);
  bf16*   XS   = (bf16*)alloc((size_t)BL * 1536 * 2);     // [Sr|Si|x]
  bf16*   Bu   = (bf16*)alloc((size_t)BL * 512 * 2);
  // gelu buffer (8192x4096 bf16 = 64 MB) aliases XS+Bu (dead by MLP time)
  bf16*   Hbf  = XS;

  float* out = (float*)d_out;
  float* st  = out + (size_t)BL * DM;

  phaseA<<<1, 256, 0, stream>>>(nu_log, th_log, scal);
  prep_bu<<<512 * 1024 / 256, 256, 0, stream>>>(B_re, B_im, scal, WBbu);
  prep_y<<<1024 * 1536 / 256, 256, 0, stream>>>(C_re, C_im, D_mat, WBy);
  transpose_to_bf16<<<dim3(4096 / 32, 1024 / 32), dim3(32, 8), 0, stream>>>(W1, WB1, 1024, 4096);
  transpose_to_bf16<<<dim3(1024 / 32, 4096 / 32), dim3(32, 8), 0, stream>>>(W2, WB2, 4096, 1024);
  conv_x<<<BL * 256 / 256, 256, 0, stream>>>((const float4*)x, XS);

  // Bu = x @ [gammaB]^T  (M=16384, N=512, K=1024): 128x256 tiles -> 256 blocks
  gemm128<0><<<128 * 2, 512, 0, stream>>>(
      XS + 512, 1536, WBbu, 1024, Bu, 512, 16, 128, 2, nullptr, nullptr);

  scan_pass1<<<B_ * NC, 256, 0, stream>>>(Bu, scal, H);
  scan_pass2<<<B_, 256, 0, stream>>>(H, scal, Cr);
  scan_pass3<<<B_ * NC, 256, 0, stream>>>(Bu, scal, Cr, XS, st);

  // y = [Sr|Si|x] @ [C_re|-C_im|D]^T  (M=16384, N=1024, K=1536): 256^2, 256 blk
  gemm256<0><<<64 * 4, 512, 0, stream>>>(
      XS, 1536, WBy, 1536, Ybf, 1024, 24, 64, 4, nullptr, nullptr);

  // MLP, M-chunked by 8192 rows (2 chunks)
  for (int i = 0; i < 2; i++) {
    const bf16* Yc = Ybf + (size_t)i * 8192 * 1024;
    float* Oc = out + (size_t)i * 8192 * 1024;
    const float* Xc = x + (size_t)i * 8192 * 1024;
    // MLP1: M=8192, N=4096, K=1024 -> 256^2, 512 blocks (2 rounds)
    gemm256<1><<<32 * 16, 512, 0, stream>>>(
        Yc, 1024, WB1, 1024, Hbf, 4096, 16, 32, 16, nullptr, nullptr);
    // MLP2: M=8192, N=1024, K=4096 -> 128x256 tiles, 256 blocks (full GPU)
    gemm128<2><<<64 * 4, 512, 0, stream>>>(
        Hbf, 4096, WB2, 4096, Oc, 1024, 64, 64, 4, Xc, reslog);
  }
}

// Round 5
// 561.683 us; speedup vs baseline: 1.2872x; 1.0143x over previous
//
#include <hip/hip_runtime.h>
#include <stdint.h>

typedef __bf16 bf16;
typedef bf16 bf16x8 __attribute__((ext_vector_type(8)));
typedef float f32x4 __attribute__((ext_vector_type(4)));

#define B_  4
#define L_  4096
#define DM  1024
#define DS  256
#define DH  4096
#define BL  16384   // B_*L_
#define CL  64      // scan chunk length
#define NC  64      // chunks per sequence

__device__ __forceinline__ float bfbits(uint32_t lo16) {
  union { uint32_t u; float f; } v; v.u = lo16 << 16; return v.f;
}

__device__ __forceinline__ void async16(const bf16* g, bf16* l) {
  __builtin_amdgcn_global_load_lds(
      (const __attribute__((address_space(1))) uint32_t*)g,
      (__attribute__((address_space(3))) uint32_t*)l, 16, 0, 0);
}

#define MEMFENCE()  asm volatile("" ::: "memory")
#define SYNC_PRE()  do { MEMFENCE(); __builtin_amdgcn_s_barrier(); } while (0)
#define SYNC_POST() do { __builtin_amdgcn_s_barrier(); MEMFENCE(); } while (0)
#define LGKM0()     asm volatile("s_waitcnt lgkmcnt(0)" ::: "memory")

// ---------------- Phase A ----------------
__global__ void phaseA(const float* __restrict__ nu_log,
                       const float* __restrict__ th_log,
                       float* __restrict__ scal) {
  int n = threadIdx.x;
  float nu = __expf(nu_log[n]);
  float th = __expf(th_log[n]);
  float mod = __expf(-nu);
  float lr = mod * cosf(th);
  float li = mod * sinf(th);
  float g = sqrtf(fmaxf(1.0f - mod * mod, 0.0f));
  float pr = 1.f, pi = 0.f;
  for (int i = 0; i < CL; i++) {
    float nr = pr * lr - pi * li;
    float ni = pr * li + pi * lr;
    pr = nr; pi = ni;
  }
  scal[n] = lr; scal[256 + n] = li;
  scal[512 + n] = pr; scal[768 + n] = pi;
  scal[1024 + n] = g;
}

// ---------------- Weight prep ----------------
__global__ void prep_bu(const float* __restrict__ B_re, const float* __restrict__ B_im,
                        const float* __restrict__ scal, bf16* __restrict__ WB) {
  size_t i = (size_t)blockIdx.x * 256 + threadIdx.x;   // over 512*1024
  int row = (int)(i >> 10), col = (int)(i & 1023);
  int n = row >> 1;
  const float* src = (row & 1) ? B_im : B_re;
  WB[i] = (bf16)(scal[1024 + n] * src[n * 1024 + col]);
}

__global__ void prep_y(const float* __restrict__ C_re, const float* __restrict__ C_im,
                       const float* __restrict__ D_mat, bf16* __restrict__ WB) {
  size_t i = (size_t)blockIdx.x * 256 + threadIdx.x;   // over 1024*1536
  int m = (int)(i / 1536), c = (int)(i % 1536);
  float v;
  if (c < 256)       v = C_re[m * 256 + c];
  else if (c < 512)  v = -C_im[m * 256 + (c - 256)];
  else               v = D_mat[m * 1024 + (c - 512)];
  WB[i] = (bf16)v;
}

__global__ void transpose_to_bf16(const float* __restrict__ in, bf16* __restrict__ out,
                                  int R, int C) {
  __shared__ float tile[32][33];
  int c0 = blockIdx.x * 32, r0 = blockIdx.y * 32;
  int tx = threadIdx.x, ty = threadIdx.y;
  for (int i = 0; i < 32; i += 8)
    tile[ty + i][tx] = in[(size_t)(r0 + ty + i) * C + c0 + tx];
  __syncthreads();
  for (int i = 0; i < 32; i += 8)
    out[(size_t)(c0 + ty + i) * R + r0 + tx] = (bf16)tile[tx][ty + i];
}

__global__ void conv_x(const float4* __restrict__ x, bf16* __restrict__ XS) {
  size_t i = (size_t)blockIdx.x * 256 + threadIdx.x;  // float4 index
  size_t t = i >> 8;
  int d4 = (int)(i & 255);
  float4 v = x[i];
  bf16* o = XS + t * 1536 + 512 + (size_t)d4 * 4;
  o[0] = (bf16)v.x; o[1] = (bf16)v.y; o[2] = (bf16)v.z; o[3] = (bf16)v.w;
}

// Shared epilogue. EPI: 0 = bf16 store, 1 = gelu->bf16, 2 = xres + sig*acc (f32)
template <int EPI>
__device__ __forceinline__ void epi_store(void* C, int ldc, size_t row, size_t col,
                                          float v, float sig, const float* xres) {
  size_t off = row * (size_t)ldc + col;
  if (EPI == 0) {
    ((bf16*)C)[off] = (bf16)v;
  } else if (EPI == 1) {
    float z = 0.7978845608f * (v + 0.044715f * v * v * v);
    float gv = v / (1.f + __expf(-2.f * z));   // v*0.5*(1+tanh(z))
    ((bf16*)C)[off] = (bf16)gv;
  } else {
    ((float*)C)[off] = xres[off] + sig * v;
  }
}

// ---------------- GEMM 256x256: C[m,n] = sum_k A[m,k] * Bt[n,k] -------------
// BK=64, 8 waves (2M x 4N), per-wave 128x64 (8x4 mfma 16x16x32).
// COUNTED-VMCNT 4-phase/K-tile schedule (m201-style):
//  p1: read a0-3 k0,k1 (8) + b0-1 k0,k1 (4); stage A(kt+1) [4gl, other dbuf]
//      | bar | lgkm | 16 MFMA (m0-3 x n0-1) | bar
//  p2: read b2-3 k0,k1 (4) | bar | lgkm | 16 MFMA (m0-3 x n2-3) | bar
//  p3: read a4-7 k0,k1 (8); stage B(kt+2,h0) | bar | lgkm | 16 MFMA (m4-7 n0-1) | bar
//  p4: stage B(kt+2,h1); vmcnt(4) | bar | 16 MFMA (m4-7 n2-3) | bar
// Hazards (verified): A last read p3, B last read p2 -> A(kt+1) stage @p1 hits
// other dbuf (occupant last read prev p3); B(kt+2) @p3/p4 hits cur dbuf-B
// (last read p2). Cert: kt's p4 vmcnt(4) leaves only p3/p4's B-stages ->
// A(kt+1) (p1) and B(kt+1) (prev p3/p4) drained before (kt+1) p1 reads.
// Tail: kt=NK-2 -> vmcnt(0) at p4; kt=NK-1 -> no stages/waits.
// LDS swizzle (verified R4): elem (r,c) at phys col c ^ ((r&7)<<3), applied on
// the GLOBAL source (linear LDS dest) and on every ds_read col; XOR wraps the
// FULL col offset incl. the +32 k1 shift.
template <int EPI>
__global__ __launch_bounds__(512, 2) void gemm256(
    const bf16* __restrict__ A, int lda,
    const bf16* __restrict__ Bt, int ldb,
    void* __restrict__ C, int ldc, int NK, int mt, int nt,
    const float* __restrict__ xres, const float* __restrict__ reslog) {
  __shared__ __align__(16) bf16 sA[2 * 16384];   // [dbuf][2 half][128][64] 64KB
  __shared__ __align__(16) bf16 sB[2 * 16384];   // 64KB

  const int tid  = threadIdx.x;
  const int lane = tid & 63;
  const int wave = tid >> 6;
  const int q = lane >> 4, l16 = lane & 15;
  const int wr = wave >> 2, wc = wave & 3;   // 2 x 4 wave grid

  // XCD tile swizzle (nb % 8 == 0, mt % 8 == 0 for all our shapes)
  int nb = mt * nt;
  int per = nb >> 3;
  int t0 = (blockIdx.x & 7) * per + (blockIdx.x >> 3);
  int gsz = nt << 3;
  int g = t0 / gsz, r = t0 % gsz;
  size_t m0 = (size_t)(g * 8 + (r & 7)) * 256;
  size_t n0 = (size_t)(r >> 3) * 256;

  const int srow = tid >> 3;                                   // 0..63
  const int scol = (((tid & 7) ^ ((tid >> 3) & 7)) << 3);
  const bf16* gA = A  + (m0 + srow) * (size_t)lda + scol;
  const bf16* gB = Bt + (n0 + srow) * (size_t)ldb + scol;
  bf16* lA = sA + tid * 8;
  bf16* lB = sB + tid * 8;

  auto stageA = [&](int kt) {          // whole 256x64 A tile (4 gl) -> dbuf kt&1
    const bf16* s = gA + kt * 64;
    bf16* l = lA + (kt & 1) * 16384;
    async16(s, l);
    async16(s + (size_t)64  * lda, l + 4096);
    async16(s + (size_t)128 * lda, l + 8192);
    async16(s + (size_t)192 * lda, l + 12288);
  };
  auto stageB = [&](int kt, int h) {   // B half-tile h (2 gl)
    const bf16* s = gB + (size_t)(h * 128) * ldb + kt * 64;
    bf16* l = lB + (kt & 1) * 16384 + h * 8192;
    async16(s, l);
    async16(s + (size_t)64 * ldb, l + 4096);
  };

  // prologue: A(0) [4gl], B(0) [4gl], B(1) [4gl]; vmcnt(4) leaves B(1)
  stageA(0); stageB(0, 0); stageB(0, 1);
  stageB(1, 0); stageB(1, 1);
  __builtin_amdgcn_s_waitcnt(0x0F74);
  __builtin_amdgcn_s_barrier();
  MEMFENCE();

  const int sw  = (l16 & 7) << 3;
  const int qx0 = (q << 3) ^ sw;
  const int qx1 = ((q << 3) + 32) ^ sw;
  const bf16* Ard = sA + wr * 8192 + l16 * 64;
  const bf16* Brd = sB + (wc >> 1) * 8192 + ((wc & 1) * 64 + l16) * 64;

  f32x4 acc[8][4] = {};
  bf16x8 a[4][2], b[4][2];

  for (int kt = 0; kt < NK; ++kt) {
    const int d = (kt & 1) * 16384;
    const bf16* Ab = Ard + d;
    const bf16* Bb = Brd + d;

    // ---- p1: reads a0-3 + b0-1; stage A(kt+1); MFMA (m0-3, n0-1) ----
#pragma unroll
    for (int j = 0; j < 4; ++j) {
      a[j][0] = *(const bf16x8*)&Ab[j * 1024 + qx0];
      a[j][1] = *(const bf16x8*)&Ab[j * 1024 + qx1];
    }
#pragma unroll
    for (int n = 0; n < 2; ++n) {
      b[n][0] = *(const bf16x8*)&Bb[n * 1024 + qx0];
      b[n][1] = *(const bf16x8*)&Bb[n * 1024 + qx1];
    }
    if (kt + 1 < NK) stageA(kt + 1);
    SYNC_PRE(); LGKM0();
    __builtin_amdgcn_s_setprio(1);
#pragma unroll
    for (int j = 0; j < 4; ++j)
#pragma unroll
      for (int n = 0; n < 2; ++n) {
        acc[j][n] = __builtin_amdgcn_mfma_f32_16x16x32_bf16(a[j][0], b[n][0], acc[j][n], 0, 0, 0);
        acc[j][n] = __builtin_amdgcn_mfma_f32_16x16x32_bf16(a[j][1], b[n][1], acc[j][n], 0, 0, 0);
      }
    __builtin_amdgcn_s_setprio(0);
    SYNC_POST();

    // ---- p2: reads b2-3; MFMA (m0-3, n2-3) ----
#pragma unroll
    for (int n = 2; n < 4; ++n) {
      b[n][0] = *(const bf16x8*)&Bb[n * 1024 + qx0];
      b[n][1] = *(const bf16x8*)&Bb[n * 1024 + qx1];
    }
    SYNC_PRE(); LGKM0();
    __builtin_amdgcn_s_setprio(1);
#pragma unroll
    for (int j = 0; j < 4; ++j)
#pragma unroll
      for (int n = 2; n < 4; ++n) {
        acc[j][n] = __builtin_amdgcn_mfma_f32_16x16x32_bf16(a[j][0], b[n][0], acc[j][n], 0, 0, 0);
        acc[j][n] = __builtin_amdgcn_mfma_f32_16x16x32_bf16(a[j][1], b[n][1], acc[j][n], 0, 0, 0);
      }
    __builtin_amdgcn_s_setprio(0);
    SYNC_POST();

    // ---- p3: reads a4-7; stage B(kt+2,h0); MFMA (m4-7, n0-1) ----
#pragma unroll
    for (int j = 0; j < 4; ++j) {
      a[j][0] = *(const bf16x8*)&Ab[(4 + j) * 1024 + qx0];
      a[j][1] = *(const bf16x8*)&Ab[(4 + j) * 1024 + qx1];
    }
    if (kt + 2 < NK) stageB(kt + 2, 0);
    SYNC_PRE(); LGKM0();
    __builtin_amdgcn_s_setprio(1);
#pragma unroll
    for (int j = 0; j < 4; ++j)
#pragma unroll
      for (int n = 0; n < 2; ++n) {
        acc[4 + j][n] = __builtin_amdgcn_mfma_f32_16x16x32_bf16(a[j][0], b[n][0], acc[4 + j][n], 0, 0, 0);
        acc[4 + j][n] = __builtin_amdgcn_mfma_f32_16x16x32_bf16(a[j][1], b[n][1], acc[4 + j][n], 0, 0, 0);
      }
    __builtin_amdgcn_s_setprio(0);
    SYNC_POST();

    // ---- p4: stage B(kt+2,h1); counted vmcnt; MFMA (m4-7, n2-3) ----
    if (kt + 2 < NK) {
      stageB(kt + 2, 1);
      __builtin_amdgcn_s_waitcnt(0x0F74);   // vmcnt(4): keep B(kt+2) in flight
    } else if (kt + 1 < NK) {
      __builtin_amdgcn_s_waitcnt(0x0F70);   // vmcnt(0): certify tail stages
    }
    SYNC_PRE();
    __builtin_amdgcn_s_setprio(1);
#pragma unroll
    for (int j = 0; j < 4; ++j)
#pragma unroll
      for (int n = 2; n < 4; ++n) {
        acc[4 + j][n] = __builtin_amdgcn_mfma_f32_16x16x32_bf16(a[j][0], b[n][0], acc[4 + j][n], 0, 0, 0);
        acc[4 + j][n] = __builtin_amdgcn_mfma_f32_16x16x32_bf16(a[j][1], b[n][1], acc[4 + j][n], 0, 0, 0);
      }
    __builtin_amdgcn_s_setprio(0);
    SYNC_POST();
  }

  float sig = 0.f;
  if (EPI == 2) sig = 1.f / (1.f + __expf(-reslog[0]));
#pragma unroll
  for (int mi = 0; mi < 8; ++mi)
#pragma unroll
    for (int ni = 0; ni < 4; ++ni) {
      size_t col = n0 + wc * 64 + ni * 16 + l16;
#pragma unroll
      for (int r2 = 0; r2 < 4; ++r2) {
        size_t row = m0 + wr * 128 + mi * 16 + q * 4 + r2;
        epi_store<EPI>(C, ldc, row, col, acc[mi][ni][r2], sig, xres);
      }
    }
}

// ---------------- GEMM 128x256 (wide-grid shapes: Bu, MLP2) -----------------
// 8 waves (2M x 4N), wave-tile 64x64. COUNTED-VMCNT 2-phase/K-tile with
// TRIPLE-buffered LDS (stage distance 2, never touches a live buffer):
//  p1: read a0-3 k0,k1 (8) + b0-1 (4); stage B(kt+2) h0,h1 [4gl]
//      | bar | lgkm | 16 MFMA (n0-1) | bar
//  p2: read b2-3 (4); stage A(kt+2) [2gl]; vmcnt(6) | bar | lgkm |
//      16 MFMA (n2-3) | bar
// Cert: kt's p2 vmcnt(6) leaves kt's own 6 loads -> K-tile kt+1's stages
// (issued kt-1) drained before (kt+1) p1. WAR: buf (kt+2)%3 occupant was
// K-tile kt-1, last read at (kt-1)'s phases -> strictly earlier. Tail:
// kt=NK-2 -> vmcnt(0); kt=NK-1 -> none.
// LDS: A 3x16KB + B 3x32KB = 144KB.
template <int EPI>
__global__ __launch_bounds__(512, 2) void gemm128(
    const bf16* __restrict__ A, int lda,
    const bf16* __restrict__ Bt, int ldb,
    void* __restrict__ C, int ldc, int NK, int mt, int nt,
    const float* __restrict__ xres, const float* __restrict__ reslog) {
  __shared__ __align__(16) bf16 sA[3 * 8192];    // 48 KB
  __shared__ __align__(16) bf16 sB[3 * 16384];   // 96 KB

  const int tid  = threadIdx.x;
  const int lane = tid & 63;
  const int wave = tid >> 6;
  const int q = lane >> 4, l16 = lane & 15;
  const int wr = wave >> 2, wc = wave & 3;

  int nb = mt * nt;
  int per = nb >> 3;
  int t0 = (blockIdx.x & 7) * per + (blockIdx.x >> 3);
  int gsz = nt << 3;
  int g = t0 / gsz, r = t0 % gsz;
  size_t m0 = (size_t)(g * 8 + (r & 7)) * 128;
  size_t n0 = (size_t)(r >> 3) * 256;

  const int srow = tid >> 3;
  const int scol = (((tid & 7) ^ ((tid >> 3) & 7)) << 3);
  const bf16* gA = A  + (m0 + srow) * (size_t)lda + scol;
  const bf16* gB = Bt + (n0 + srow) * (size_t)ldb + scol;
  bf16* lA = sA + tid * 8;
  bf16* lB = sB + tid * 8;

  auto stageA = [&](int kt, int buf) {          // 128x64 A tile (2 gl)
    const bf16* s = gA + kt * 64;
    bf16* l = lA + buf * 8192;
    async16(s, l);
    async16(s + (size_t)64 * lda, l + 4096);
  };
  auto stageB = [&](int kt, int buf, int h) {   // B half-tile h (2 gl)
    const bf16* s = gB + (size_t)(h * 128) * ldb + kt * 64;
    bf16* l = lB + buf * 16384 + h * 8192;
    async16(s, l);
    async16(s + (size_t)64 * ldb, l + 4096);
  };

  // prologue: K0 (6 gl) then K1 (6 gl); vmcnt(6) leaves K1
  stageB(0, 0, 0); stageB(0, 0, 1); stageA(0, 0);
  stageB(1, 1, 0); stageB(1, 1, 1); stageA(1, 1);
  __builtin_amdgcn_s_waitcnt(0x0F76);
  __builtin_amdgcn_s_barrier();
  MEMFENCE();

  const int sw  = (l16 & 7) << 3;
  const int qx0 = (q << 3) ^ sw;
  const int qx1 = ((q << 3) + 32) ^ sw;
  const bf16* Ard = sA + (wr * 64 + l16) * 64;
  const bf16* Brd = sB + (wc >> 1) * 8192 + ((wc & 1) * 64 + l16) * 64;

  f32x4 acc[4][4] = {};
  bf16x8 a[4][2], b[4][2];

  int c0 = 0, c2 = 2;   // buf of kt, buf of kt+2
  for (int kt = 0; kt < NK; ++kt) {
    const bf16* Ab = Ard + c0 * 8192;
    const bf16* Bb = Brd + c0 * 16384;

    // ---- p1: reads a0-3 + b0-1; stage B(kt+2); MFMA n0-1 ----
#pragma unroll
    for (int j = 0; j < 4; ++j) {
      a[j][0] = *(const bf16x8*)&Ab[j * 1024 + qx0];
      a[j][1] = *(const bf16x8*)&Ab[j * 1024 + qx1];
    }
#pragma unroll
    for (int n = 0; n < 2; ++n) {
      b[n][0] = *(const bf16x8*)&Bb[n * 1024 + qx0];
      b[n][1] = *(const bf16x8*)&Bb[n * 1024 + qx1];
    }
    if (kt + 2 < NK) { stageB(kt + 2, c2, 0); stageB(kt + 2, c2, 1); }
    SYNC_PRE(); LGKM0();
    __builtin_amdgcn_s_setprio(1);
#pragma unroll
    for (int j = 0; j < 4; ++j)
#pragma unroll
      for (int n = 0; n < 2; ++n) {
        acc[j][n] = __builtin_amdgcn_mfma_f32_16x16x32_bf16(a[j][0], b[n][0], acc[j][n], 0, 0, 0);
        acc[j][n] = __builtin_amdgcn_mfma_f32_16x16x32_bf16(a[j][1], b[n][1], acc[j][n], 0, 0, 0);
      }
    __builtin_amdgcn_s_setprio(0);
    SYNC_POST();

    // ---- p2: reads b2-3; stage A(kt+2); counted vmcnt; MFMA n2-3 ----
#pragma unroll
    for (int n = 2; n < 4; ++n) {
      b[n][0] = *(const bf16x8*)&Bb[n * 1024 + qx0];
      b[n][1] = *(const bf16x8*)&Bb[n * 1024 + qx1];
    }
    if (kt + 2 < NK) {
      stageA(kt + 2, c2);
      __builtin_amdgcn_s_waitcnt(0x0F76);   // vmcnt(6): keep kt+2 in flight
    } else if (kt + 1 < NK) {
      __builtin_amdgcn_s_waitcnt(0x0F70);   // vmcnt(0): certify tail
    }
    SYNC_PRE(); LGKM0();
    __builtin_amdgcn_s_setprio(1);
#pragma unroll
    for (int j = 0; j < 4; ++j)
#pragma unroll
      for (int n = 2; n < 4; ++n) {
        acc[j][n] = __builtin_amdgcn_mfma_f32_16x16x32_bf16(a[j][0], b[n][0], acc[j][n], 0, 0, 0);
        acc[j][n] = __builtin_amdgcn_mfma_f32_16x16x32_bf16(a[j][1], b[n][1], acc[j][n], 0, 0, 0);
      }
    __builtin_amdgcn_s_setprio(0);
    SYNC_POST();

    c0 = (c0 == 2) ? 0 : c0 + 1;
    c2 = (c2 == 2) ? 0 : c2 + 1;
  }

  float sig = 0.f;
  if (EPI == 2) sig = 1.f / (1.f + __expf(-reslog[0]));
#pragma unroll
  for (int mi = 0; mi < 4; ++mi)
#pragma unroll
    for (int ni = 0; ni < 4; ++ni) {
      size_t col = n0 + wc * 64 + ni * 16 + l16;
#pragma unroll
      for (int r2 = 0; r2 < 4; ++r2) {
        size_t row = m0 + wr * 64 + mi * 16 + q * 4 + r2;
        epi_store<EPI>(C, ldc, row, col, acc[mi][ni][r2], sig, xres);
      }
    }
}

// ---------------- Scan ----------------
__global__ void scan_pass1(const bf16* __restrict__ Bu, const float* __restrict__ scal,
                           float2* __restrict__ H) {
  int b = blockIdx.x >> 6, c = blockIdx.x & 63, n = threadIdx.x;
  float lr = scal[n], li = scal[256 + n];
  float sr = 0.f, si = 0.f;
  size_t t0 = (size_t)b * L_ + (size_t)c * CL;
  const uint32_t* p = (const uint32_t*)(Bu + t0 * 512) + n;
  for (int j = 0; j < CL; j++) {
    uint32_t u = p[(size_t)j * 256];
    float ur = bfbits(u & 0xffffu), ui = bfbits(u >> 16);
    float nr = lr * sr - li * si + ur;
    float ni = lr * si + li * sr + ui;
    sr = nr; si = ni;
  }
  H[(size_t)(b * NC + c) * 256 + n] = make_float2(sr, si);
}

__global__ void scan_pass2(const float2* __restrict__ H, const float* __restrict__ scal,
                           float2* __restrict__ Carry) {
  int b = blockIdx.x, n = threadIdx.x;
  float Pr = scal[512 + n], Pi = scal[768 + n];
  float cr = 0.f, ci = 0.f;
  for (int c = 0; c < NC; c++) {
    Carry[(size_t)(b * NC + c) * 256 + n] = make_float2(cr, ci);
    float2 h = H[(size_t)(b * NC + c) * 256 + n];
    float nr = Pr * cr - Pi * ci + h.x;
    float ni = Pr * ci + Pi * cr + h.y;
    cr = nr; ci = ni;
  }
}

// st layout: PLANAR-GLOBAL — st[0..1023] = re (b-major), st[1024..2047] = im
__global__ void scan_pass3(const bf16* __restrict__ Bu, const float* __restrict__ scal,
                           const float2* __restrict__ Carry, bf16* __restrict__ XS,
                           float* __restrict__ st) {
  int b = blockIdx.x >> 6, c = blockIdx.x & 63, n = threadIdx.x;
  float lr = scal[n], li = scal[256 + n];
  float2 cv = Carry[(size_t)(b * NC + c) * 256 + n];
  float sr = cv.x, si = cv.y;
  size_t t0 = (size_t)b * L_ + (size_t)c * CL;
  const uint32_t* p = (const uint32_t*)(Bu + t0 * 512) + n;
  bf16* qp = XS + t0 * 1536 + n;
  for (int j = 0; j < CL; j++) {
    uint32_t u = p[(size_t)j * 256];
    float ur = bfbits(u & 0xffffu), ui = bfbits(u >> 16);
    float nr = lr * sr - li * si + ur;
    float ni = lr * si + li * sr + ui;
    sr = nr; si = ni;
    qp[(size_t)j * 1536] = (bf16)sr;
    qp[(size_t)j * 1536 + 256] = (bf16)si;
  }
  if (c == NC - 1) {
    st[(size_t)b * 256 + n] = sr;
    st[1024 + (size_t)b * 256 + n] = si;
  }
}

// ---------------- Launch ----------------
extern "C" void kernel_launch(void* const* d_in, const int* in_sizes, int n_in,
                              void* d_out, int out_size, void* d_ws, size_t ws_size,
                              hipStream_t stream) {
  const float* x      = (const float*)d_in[0];
  const float* nu_log = (const float*)d_in[1];
  const float* th_log = (const float*)d_in[2];
  const float* B_re   = (const float*)d_in[3];
  const float* B_im   = (const float*)d_in[4];
  const float* C_re   = (const float*)d_in[5];
  const float* C_im   = (const float*)d_in[6];
  const float* D_mat  = (const float*)d_in[7];
  const float* W1     = (const float*)d_in[8];
  const float* W2     = (const float*)d_in[9];
  const float* reslog = (const float*)d_in[10];

  char* wsb = (char*)d_ws;
  size_t off = 0;
  auto alloc = [&](size_t bytes) {
    void* p = wsb + off;
    off += (bytes + 255) & ~(size_t)255;
    return p;
  };
  float*  scal = (float*)alloc(5 * 256 * 4);
  bf16*   WBbu = (bf16*)alloc((size_t)512 * 1024 * 2);
  bf16*   WBy  = (bf16*)alloc((size_t)1024 * 1536 * 2);
  bf16*   WB1  = (bf16*)alloc((size_t)4096 * 1024 * 2);   // W1^T
  bf16*   WB2  = (bf16*)alloc((size_t)1024 * 4096 * 2);   // W2^T
  float2* H    = (float2*)alloc((size_t)B_ * NC * 256 * 8);
  float2* Cr   = (float2*)alloc((size_t)B_ * NC * 256 * 8);
  bf16*   Ybf  = (bf16*)alloc((size_t)BL * 1024 * 2);
  bf16*   XS   = (bf16*)alloc((size_t)BL * 1536 * 2);     // [Sr|Si|x]
  bf16*   Bu   = (bf16*)alloc((size_t)BL * 512 * 2);
  // gelu buffer (8192x4096 bf16 = 64 MB) aliases XS+Bu (dead by MLP time)
  bf16*   Hbf  = XS;

  float* out = (float*)d_out;
  float* st  = out + (size_t)BL * DM;

  phaseA<<<1, 256, 0, stream>>>(nu_log, th_log, scal);
  prep_bu<<<512 * 1024 / 256, 256, 0, stream>>>(B_re, B_im, scal, WBbu);
  prep_y<<<1024 * 1536 / 256, 256, 0, stream>>>(C_re, C_im, D_mat, WBy);
  transpose_to_bf16<<<dim3(4096 / 32, 1024 / 32), dim3(32, 8), 0, stream>>>(W1, WB1, 1024, 4096);
  transpose_to_bf16<<<dim3(1024 / 32, 4096 / 32), dim3(32, 8), 0, stream>>>(W2, WB2, 4096, 1024);
  conv_x<<<BL * 256 / 256, 256, 0, stream>>>((const float4*)x, XS);

  // Bu = x @ [gammaB]^T  (M=16384, N=512, K=1024): 128x256 tiles -> 256 blocks
  gemm128<0><<<128 * 2, 512, 0, stream>>>(
      XS + 512, 1536, WBbu, 1024, Bu, 512, 16, 128, 2, nullptr, nullptr);

  scan_pass1<<<B_ * NC, 256, 0, stream>>>(Bu, scal, H);
  scan_pass2<<<B_, 256, 0, stream>>>(H, scal, Cr);
  scan_pass3<<<B_ * NC, 256, 0, stream>>>(Bu, scal, Cr, XS, st);

  // y = [Sr|Si|x] @ [C_re|-C_im|D]^T  (M=16384, N=1024, K=1536): 256^2, 256 blk
  gemm256<0><<<64 * 4, 512, 0, stream>>>(
      XS, 1536, WBy, 1536, Ybf, 1024, 24, 64, 4, nullptr, nullptr);

  // MLP, M-chunked by 8192 rows (2 chunks)
  for (int i = 0; i < 2; i++) {
    const bf16* Yc = Ybf + (size_t)i * 8192 * 1024;
    float* Oc = out + (size_t)i * 8192 * 1024;
    const float* Xc = x + (size_t)i * 8192 * 1024;
    // MLP1: M=8192, N=4096, K=1024 -> 256^2, 512 blocks (2 rounds)
    gemm256<1><<<32 * 16, 512, 0, stream>>>(
        Yc, 1024, WB1, 1024, Hbf, 4096, 16, 32, 16, nullptr, nullptr);
    // MLP2: M=8192, N=1024, K=4096 -> 128x256 tiles, 256 blocks (full GPU)
    gemm128<2><<<64 * 4, 512, 0, stream>>>(
        Hbf, 4096, WB2, 4096, Oc, 1024, 64, 64, 4, Xc, reslog);
  }
}

// Round 6
// 555.867 us; speedup vs baseline: 1.3006x; 1.0105x over previous
//
#include <hip/hip_runtime.h>
#include <stdint.h>

typedef __bf16 bf16;
typedef bf16 bf16x8 __attribute__((ext_vector_type(8)));
typedef float f32x4 __attribute__((ext_vector_type(4)));

#define B_  4
#define L_  4096
#define DM  1024
#define DS  256
#define DH  4096
#define BL  16384   // B_*L_
#define CL  64      // scan chunk length
#define NC  64      // chunks per sequence

__device__ __forceinline__ float bfbits(uint32_t lo16) {
  union { uint32_t u; float f; } v; v.u = lo16 << 16; return v.f;
}

__device__ __forceinline__ void async16(const bf16* g, bf16* l) {
  __builtin_amdgcn_global_load_lds(
      (const __attribute__((address_space(1))) uint32_t*)g,
      (__attribute__((address_space(3))) uint32_t*)l, 16, 0, 0);
}

#define MEMFENCE()  asm volatile("" ::: "memory")
#define LGKM0()     asm volatile("s_waitcnt lgkmcnt(0)" ::: "memory")
#define SCHEDB()    __builtin_amdgcn_sched_barrier(0)

// ---------------- Phase A ----------------
__global__ void phaseA(const float* __restrict__ nu_log,
                       const float* __restrict__ th_log,
                       float* __restrict__ scal) {
  int n = threadIdx.x;
  float nu = __expf(nu_log[n]);
  float th = __expf(th_log[n]);
  float mod = __expf(-nu);
  float lr = mod * cosf(th);
  float li = mod * sinf(th);
  float g = sqrtf(fmaxf(1.0f - mod * mod, 0.0f));
  float pr = 1.f, pi = 0.f;
  for (int i = 0; i < CL; i++) {
    float nr = pr * lr - pi * li;
    float ni = pr * li + pi * lr;
    pr = nr; pi = ni;
  }
  scal[n] = lr; scal[256 + n] = li;
  scal[512 + n] = pr; scal[768 + n] = pi;
  scal[1024 + n] = g;
}

// ---------------- Weight prep ----------------
__global__ void prep_bu(const float* __restrict__ B_re, const float* __restrict__ B_im,
                        const float* __restrict__ scal, bf16* __restrict__ WB) {
  size_t i = (size_t)blockIdx.x * 256 + threadIdx.x;   // over 512*1024
  int row = (int)(i >> 10), col = (int)(i & 1023);
  int n = row >> 1;
  const float* src = (row & 1) ? B_im : B_re;
  WB[i] = (bf16)(scal[1024 + n] * src[n * 1024 + col]);
}

__global__ void prep_y(const float* __restrict__ C_re, const float* __restrict__ C_im,
                       const float* __restrict__ D_mat, bf16* __restrict__ WB) {
  size_t i = (size_t)blockIdx.x * 256 + threadIdx.x;   // over 1024*1536
  int m = (int)(i / 1536), c = (int)(i % 1536);
  float v;
  if (c < 256)       v = C_re[m * 256 + c];
  else if (c < 512)  v = -C_im[m * 256 + (c - 256)];
  else               v = D_mat[m * 1024 + (c - 512)];
  WB[i] = (bf16)v;
}

__global__ void transpose_to_bf16(const float* __restrict__ in, bf16* __restrict__ out,
                                  int R, int C) {
  __shared__ float tile[32][33];
  int c0 = blockIdx.x * 32, r0 = blockIdx.y * 32;
  int tx = threadIdx.x, ty = threadIdx.y;
  for (int i = 0; i < 32; i += 8)
    tile[ty + i][tx] = in[(size_t)(r0 + ty + i) * C + c0 + tx];
  __syncthreads();
  for (int i = 0; i < 32; i += 8)
    out[(size_t)(c0 + ty + i) * R + r0 + tx] = (bf16)tile[tx][ty + i];
}

__global__ void conv_x(const float4* __restrict__ x, bf16* __restrict__ XS) {
  size_t i = (size_t)blockIdx.x * 256 + threadIdx.x;  // float4 index
  size_t t = i >> 8;
  int d4 = (int)(i & 255);
  float4 v = x[i];
  bf16* o = XS + t * 1536 + 512 + (size_t)d4 * 4;
  o[0] = (bf16)v.x; o[1] = (bf16)v.y; o[2] = (bf16)v.z; o[3] = (bf16)v.w;
}

// Shared epilogue. EPI: 0 = bf16 store, 1 = gelu->bf16, 2 = xres + sig*acc (f32)
template <int EPI>
__device__ __forceinline__ void epi_store(void* C, int ldc, size_t row, size_t col,
                                          float v, float sig, const float* xres) {
  size_t off = row * (size_t)ldc + col;
  if (EPI == 0) {
    ((bf16*)C)[off] = (bf16)v;
  } else if (EPI == 1) {
    float z = 0.7978845608f * (v + 0.044715f * v * v * v);
    float gv = v / (1.f + __expf(-2.f * z));   // v*0.5*(1+tanh(z))
    ((bf16*)C)[off] = (bf16)gv;
  } else {
    ((float*)C)[off] = xres[off] + sig * v;
  }
}

// ---------------- GEMM 256x256: C[m,n] = sum_k A[m,k] * Bt[n,k] -------------
// BK=64, 8 waves (2M x 4N), per-wave 128x64 (8x4 mfma 16x16x32).
// K-MAJOR READ-AHEAD schedule: each phase ISSUES the next phase's ds_reads
// (into fragment regs that just died), then MFMAs fragments read one phase
// earlier -- reads get a full MFMA phase (~620cyc) to drain, so they never
// stall. Fragments: a0,a1,b0,b1[4] (k0/k1 halves; 64 VGPR, same as before).
//  P1: rd a1<-(m0-3,k1), b1<-k1      | MFMA a0(m0-3) x b0 -> acc[0-3]  (k0)
//  P2: rd a0<-(m4-7,k0)              | MFMA a1(m0-3) x b1 -> acc[0-3]  (k1)
//  P3: rd a1<-(m4-7,k1)              | MFMA a0(m4-7) x b0 -> acc[4-7]  (k0)
//  SYNC: vmcnt(0) [drains DMA(kt+1), issued 3 phases ago -> free];
//        lgkm0 [P3 reads had P3 MFMA -> free]; s_barrier.  ONE sync/tile.
//  P4: rd a0<-(m0-3,k0,kt+1), b0<-(k0,kt+1) from other dbuf [certified by
//      SYNC]; issue DMA A(kt+2)+B(kt+2) [8 gl]; MFMA a1(m4-7) x b1 -> acc[4-7]
// WAR: buffer(kt-parity) last read at P3(kt), drained at SYNC(kt); DMA(kt+2)
// into it issues after -> safe. DMA(kt+2) drains at SYNC(kt+1), 3 phases later.
// LDS swizzle: elem (r,c) at phys col c ^ ((r&7)<<3), applied on the GLOBAL
// source (linear LDS dest) and on every ds_read col; XOR wraps the FULL col
// offset incl. the +32 k1 shift.
template <int EPI>
__global__ __launch_bounds__(512, 2) void gemm256(
    const bf16* __restrict__ A, int lda,
    const bf16* __restrict__ Bt, int ldb,
    void* __restrict__ C, int ldc, int NK, int mt, int nt,
    const float* __restrict__ xres, const float* __restrict__ reslog) {
  __shared__ __align__(16) bf16 sA[2 * 16384];   // [dbuf][2 half][128][64] 64KB
  __shared__ __align__(16) bf16 sB[2 * 16384];   // 64KB

  const int tid  = threadIdx.x;
  const int lane = tid & 63;
  const int wave = tid >> 6;
  const int q = lane >> 4, l16 = lane & 15;
  const int wr = wave >> 2, wc = wave & 3;   // 2 x 4 wave grid

  // XCD tile swizzle (nb % 8 == 0, mt % 8 == 0 for all our shapes)
  int nb = mt * nt;
  int per = nb >> 3;
  int t0 = (blockIdx.x & 7) * per + (blockIdx.x >> 3);
  int gsz = nt << 3;
  int g = t0 / gsz, r = t0 % gsz;
  size_t m0 = (size_t)(g * 8 + (r & 7)) * 256;
  size_t n0 = (size_t)(r >> 3) * 256;

  const int srow = tid >> 3;                                   // 0..63
  const int scol = (((tid & 7) ^ ((tid >> 3) & 7)) << 3);
  const bf16* gA = A  + (m0 + srow) * (size_t)lda + scol;
  const bf16* gB = Bt + (n0 + srow) * (size_t)ldb + scol;
  bf16* lA = sA + tid * 8;
  bf16* lB = sB + tid * 8;

  auto stageA = [&](int kt) {          // whole 256x64 A tile (4 gl) -> dbuf kt&1
    const bf16* s = gA + kt * 64;
    bf16* l = lA + (kt & 1) * 16384;
    async16(s, l);
    async16(s + (size_t)64  * lda, l + 4096);
    async16(s + (size_t)128 * lda, l + 8192);
    async16(s + (size_t)192 * lda, l + 12288);
  };
  auto stageB = [&](int kt) {
    const bf16* s = gB + kt * 64;
    bf16* l = lB + (kt & 1) * 16384;
    async16(s, l);
    async16(s + (size_t)64  * ldb, l + 4096);
    async16(s + (size_t)128 * ldb, l + 8192);
    async16(s + (size_t)192 * ldb, l + 12288);
  };

  // prologue: tiles 0 and 1 (16 gl); vmcnt(8) -> tile 0 landed
  stageA(0); stageB(0); stageA(1); stageB(1);
  __builtin_amdgcn_s_waitcnt(0x0F78);
  __builtin_amdgcn_s_barrier();
  MEMFENCE();

  const int sw  = (l16 & 7) << 3;
  const int qx0 = (q << 3) ^ sw;
  const int qx1 = ((q << 3) + 32) ^ sw;
  const bf16* Ard = sA + wr * 8192 + l16 * 64;
  const bf16* Brd = sB + (wc >> 1) * 8192 + ((wc & 1) * 64 + l16) * 64;

  f32x4 acc[8][4] = {};
  bf16x8 a0[4], a1[4], b0[4], b1[4];

  // pre-read: tile0 (m0-3, k0) + b k0
#pragma unroll
  for (int j = 0; j < 4; ++j) a0[j] = *(const bf16x8*)&Ard[j * 1024 + qx0];
#pragma unroll
  for (int n = 0; n < 4; ++n) b0[n] = *(const bf16x8*)&Brd[n * 1024 + qx0];

  for (int kt = 0; kt < NK; ++kt) {
    const bf16* Ab  = Ard + (kt & 1) * 16384;
    const bf16* Bb  = Brd + (kt & 1) * 16384;
    const bf16* Abn = Ard + ((kt + 1) & 1) * 16384;
    const bf16* Bbn = Brd + ((kt + 1) & 1) * 16384;

    // ---- P1: rd a1(m0-3,k1)+b1(k1) | MFMA a0(m0-3) x b0 (k0) ----
#pragma unroll
    for (int j = 0; j < 4; ++j) a1[j] = *(const bf16x8*)&Ab[j * 1024 + qx1];
#pragma unroll
    for (int n = 0; n < 4; ++n) b1[n] = *(const bf16x8*)&Bb[n * 1024 + qx1];
    SCHEDB();
    __builtin_amdgcn_s_setprio(1);
#pragma unroll
    for (int j = 0; j < 4; ++j)
#pragma unroll
      for (int n = 0; n < 4; ++n)
        acc[j][n] = __builtin_amdgcn_mfma_f32_16x16x32_bf16(a0[j], b0[n], acc[j][n], 0, 0, 0);
    __builtin_amdgcn_s_setprio(0);

    // ---- P2: rd a0<-(m4-7,k0) | MFMA a1(m0-3) x b1 (k1) ----
#pragma unroll
    for (int j = 0; j < 4; ++j) a0[j] = *(const bf16x8*)&Ab[(4 + j) * 1024 + qx0];
    SCHEDB();
    __builtin_amdgcn_s_setprio(1);
#pragma unroll
    for (int j = 0; j < 4; ++j)
#pragma unroll
      for (int n = 0; n < 4; ++n)
        acc[j][n] = __builtin_amdgcn_mfma_f32_16x16x32_bf16(a1[j], b1[n], acc[j][n], 0, 0, 0);
    __builtin_amdgcn_s_setprio(0);

    // ---- P3: rd a1<-(m4-7,k1) | MFMA a0(m4-7) x b0 (k0) ----
#pragma unroll
    for (int j = 0; j < 4; ++j) a1[j] = *(const bf16x8*)&Ab[(4 + j) * 1024 + qx1];
    SCHEDB();
    __builtin_amdgcn_s_setprio(1);
#pragma unroll
    for (int j = 0; j < 4; ++j)
#pragma unroll
      for (int n = 0; n < 4; ++n)
        acc[4 + j][n] = __builtin_amdgcn_mfma_f32_16x16x32_bf16(a0[j], b0[n], acc[4 + j][n], 0, 0, 0);
    __builtin_amdgcn_s_setprio(0);

    // ---- SYNC (once per K-tile) ----
    MEMFENCE();
    __builtin_amdgcn_s_waitcnt(0x0F70);   // drains DMA(kt+1), issued 3 phases ago
    LGKM0();
    __builtin_amdgcn_s_barrier();
    MEMFENCE();

    // ---- P4: rd a0,b0 <- (kt+1, k0); issue DMA(kt+2); MFMA a1(m4-7) x b1 ----
    if (kt + 1 < NK) {
#pragma unroll
      for (int j = 0; j < 4; ++j) a0[j] = *(const bf16x8*)&Abn[j * 1024 + qx0];
#pragma unroll
      for (int n = 0; n < 4; ++n) b0[n] = *(const bf16x8*)&Bbn[n * 1024 + qx0];
    }
    if (kt + 2 < NK) { stageA(kt + 2); stageB(kt + 2); }
    SCHEDB();
    __builtin_amdgcn_s_setprio(1);
#pragma unroll
    for (int j = 0; j < 4; ++j)
#pragma unroll
      for (int n = 0; n < 4; ++n)
        acc[4 + j][n] = __builtin_amdgcn_mfma_f32_16x16x32_bf16(a1[j], b1[n], acc[4 + j][n], 0, 0, 0);
    __builtin_amdgcn_s_setprio(0);
  }

  float sig = 0.f;
  if (EPI == 2) sig = 1.f / (1.f + __expf(-reslog[0]));
#pragma unroll
  for (int mi = 0; mi < 8; ++mi)
#pragma unroll
    for (int ni = 0; ni < 4; ++ni) {
      size_t col = n0 + wc * 64 + ni * 16 + l16;
#pragma unroll
      for (int r2 = 0; r2 < 4; ++r2) {
        size_t row = m0 + wr * 128 + mi * 16 + q * 4 + r2;
        epi_store<EPI>(C, ldc, row, col, acc[mi][ni][r2], sig, xres);
      }
    }
}

// ---------------- GEMM 128x256 (wide-grid shapes: Bu, MLP2) -----------------
// 8 waves (2M x 4N), wave-tile 64x64. K-major read-ahead, 2 phases/tile:
//  P1: rd a1(kt,k1)+b1(kt,k1) [8]  | MFMA a0 x b0 (k0)
//  SYNC: vmcnt(0) [DMA(kt+1) issued P2(kt-1) -> ~free]; lgkm0; barrier
//  P2: rd a0,b0 <- (kt+1, k0) [8, certified]; issue DMA(kt+2) [6 gl];
//      MFMA a1 x b1 (k1)
// WAR: buffer(kt) last read P1(kt), drained at SYNC(kt); DMA(kt+2) into it
// issues after -> 2 dbufs suffice. LDS: A 2x16KB + B 2x32KB = 96 KB.
template <int EPI>
__global__ __launch_bounds__(512, 2) void gemm128(
    const bf16* __restrict__ A, int lda,
    const bf16* __restrict__ Bt, int ldb,
    void* __restrict__ C, int ldc, int NK, int mt, int nt,
    const float* __restrict__ xres, const float* __restrict__ reslog) {
  __shared__ __align__(16) bf16 sA[2 * 8192];    // 32 KB
  __shared__ __align__(16) bf16 sB[2 * 16384];   // 64 KB

  const int tid  = threadIdx.x;
  const int lane = tid & 63;
  const int wave = tid >> 6;
  const int q = lane >> 4, l16 = lane & 15;
  const int wr = wave >> 2, wc = wave & 3;

  int nb = mt * nt;
  int per = nb >> 3;
  int t0 = (blockIdx.x & 7) * per + (blockIdx.x >> 3);
  int gsz = nt << 3;
  int g = t0 / gsz, r = t0 % gsz;
  size_t m0 = (size_t)(g * 8 + (r & 7)) * 128;
  size_t n0 = (size_t)(r >> 3) * 256;

  const int srow = tid >> 3;
  const int scol = (((tid & 7) ^ ((tid >> 3) & 7)) << 3);
  const bf16* gA = A  + (m0 + srow) * (size_t)lda + scol;
  const bf16* gB = Bt + (n0 + srow) * (size_t)ldb + scol;
  bf16* lA = sA + tid * 8;
  bf16* lB = sB + tid * 8;

  auto stageA = [&](int kt) {          // 128x64 A tile (2 gl)
    const bf16* s = gA + kt * 64;
    bf16* l = lA + (kt & 1) * 8192;
    async16(s, l);
    async16(s + (size_t)64 * lda, l + 4096);
  };
  auto stageB = [&](int kt) {          // 256x64 B tile (4 gl)
    const bf16* s = gB + kt * 64;
    bf16* l = lB + (kt & 1) * 16384;
    async16(s, l);
    async16(s + (size_t)64  * ldb, l + 4096);
    async16(s + (size_t)128 * ldb, l + 8192);
    async16(s + (size_t)192 * ldb, l + 12288);
  };

  // prologue: tiles 0,1 (12 gl); vmcnt(6) -> tile 0 landed
  stageA(0); stageB(0); stageA(1); stageB(1);
  __builtin_amdgcn_s_waitcnt(0x0F76);
  __builtin_amdgcn_s_barrier();
  MEMFENCE();

  const int sw  = (l16 & 7) << 3;
  const int qx0 = (q << 3) ^ sw;
  const int qx1 = ((q << 3) + 32) ^ sw;
  const bf16* Ard = sA + (wr * 64 + l16) * 64;
  const bf16* Brd = sB + (wc >> 1) * 8192 + ((wc & 1) * 64 + l16) * 64;

  f32x4 acc[4][4] = {};
  bf16x8 a0[4], a1[4], b0[4], b1[4];

  // pre-read tile0 k0
#pragma unroll
  for (int j = 0; j < 4; ++j) a0[j] = *(const bf16x8*)&Ard[j * 1024 + qx0];
#pragma unroll
  for (int n = 0; n < 4; ++n) b0[n] = *(const bf16x8*)&Brd[n * 1024 + qx0];

  for (int kt = 0; kt < NK; ++kt) {
    const bf16* Ab  = Ard + (kt & 1) * 8192;
    const bf16* Bb  = Brd + (kt & 1) * 16384;
    const bf16* Abn = Ard + ((kt + 1) & 1) * 8192;
    const bf16* Bbn = Brd + ((kt + 1) & 1) * 16384;

    // ---- P1: rd a1,b1 (k1) | MFMA a0 x b0 (k0) ----
#pragma unroll
    for (int j = 0; j < 4; ++j) a1[j] = *(const bf16x8*)&Ab[j * 1024 + qx1];
#pragma unroll
    for (int n = 0; n < 4; ++n) b1[n] = *(const bf16x8*)&Bb[n * 1024 + qx1];
    SCHEDB();
    __builtin_amdgcn_s_setprio(1);
#pragma unroll
    for (int j = 0; j < 4; ++j)
#pragma unroll
      for (int n = 0; n < 4; ++n)
        acc[j][n] = __builtin_amdgcn_mfma_f32_16x16x32_bf16(a0[j], b0[n], acc[j][n], 0, 0, 0);
    __builtin_amdgcn_s_setprio(0);

    // ---- SYNC ----
    MEMFENCE();
    __builtin_amdgcn_s_waitcnt(0x0F70);   // drains DMA(kt+1), issued P2(kt-1)
    LGKM0();
    __builtin_amdgcn_s_barrier();
    MEMFENCE();

    // ---- P2: rd a0,b0 <- (kt+1,k0); issue DMA(kt+2); MFMA a1 x b1 (k1) ----
    if (kt + 1 < NK) {
#pragma unroll
      for (int j = 0; j < 4; ++j) a0[j] = *(const bf16x8*)&Abn[j * 1024 + qx0];
#pragma unroll
      for (int n = 0; n < 4; ++n) b0[n] = *(const bf16x8*)&Bbn[n * 1024 + qx0];
    }
    if (kt + 2 < NK) { stageA(kt + 2); stageB(kt + 2); }
    SCHEDB();
    __builtin_amdgcn_s_setprio(1);
#pragma unroll
    for (int j = 0; j < 4; ++j)
#pragma unroll
      for (int n = 0; n < 4; ++n)
        acc[j][n] = __builtin_amdgcn_mfma_f32_16x16x32_bf16(a1[j], b1[n], acc[j][n], 0, 0, 0);
    __builtin_amdgcn_s_setprio(0);
  }

  float sig = 0.f;
  if (EPI == 2) sig = 1.f / (1.f + __expf(-reslog[0]));
#pragma unroll
  for (int mi = 0; mi < 4; ++mi)
#pragma unroll
    for (int ni = 0; ni < 4; ++ni) {
      size_t col = n0 + wc * 64 + ni * 16 + l16;
#pragma unroll
      for (int r2 = 0; r2 < 4; ++r2) {
        size_t row = m0 + wr * 64 + mi * 16 + q * 4 + r2;
        epi_store<EPI>(C, ldc, row, col, acc[mi][ni][r2], sig, xres);
      }
    }
}

// ---------------- Scan ----------------
__global__ void scan_pass1(const bf16* __restrict__ Bu, const float* __restrict__ scal,
                           float2* __restrict__ H) {
  int b = blockIdx.x >> 6, c = blockIdx.x & 63, n = threadIdx.x;
  float lr = scal[n], li = scal[256 + n];
  float sr = 0.f, si = 0.f;
  size_t t0 = (size_t)b * L_ + (size_t)c * CL;
  const uint32_t* p = (const uint32_t*)(Bu + t0 * 512) + n;
  for (int j = 0; j < CL; j++) {
    uint32_t u = p[(size_t)j * 256];
    float ur = bfbits(u & 0xffffu), ui = bfbits(u >> 16);
    float nr = lr * sr - li * si + ur;
    float ni = lr * si + li * sr + ui;
    sr = nr; si = ni;
  }
  H[(size_t)(b * NC + c) * 256 + n] = make_float2(sr, si);
}

__global__ void scan_pass2(const float2* __restrict__ H, const float* __restrict__ scal,
                           float2* __restrict__ Carry) {
  int b = blockIdx.x, n = threadIdx.x;
  float Pr = scal[512 + n], Pi = scal[768 + n];
  float cr = 0.f, ci = 0.f;
  for (int c = 0; c < NC; c++) {
    Carry[(size_t)(b * NC + c) * 256 + n] = make_float2(cr, ci);
    float2 h = H[(size_t)(b * NC + c) * 256 + n];
    float nr = Pr * cr - Pi * ci + h.x;
    float ni = Pr * ci + Pi * cr + h.y;
    cr = nr; ci = ni;
  }
}

// st layout: PLANAR-GLOBAL — st[0..1023] = re (b-major), st[1024..2047] = im
__global__ void scan_pass3(const bf16* __restrict__ Bu, const float* __restrict__ scal,
                           const float2* __restrict__ Carry, bf16* __restrict__ XS,
                           float* __restrict__ st) {
  int b = blockIdx.x >> 6, c = blockIdx.x & 63, n = threadIdx.x;
  float lr = scal[n], li = scal[256 + n];
  float2 cv = Carry[(size_t)(b * NC + c) * 256 + n];
  float sr = cv.x, si = cv.y;
  size_t t0 = (size_t)b * L_ + (size_t)c * CL;
  const uint32_t* p = (const uint32_t*)(Bu + t0 * 512) + n;
  bf16* qp = XS + t0 * 1536 + n;
  for (int j = 0; j < CL; j++) {
    uint32_t u = p[(size_t)j * 256];
    float ur = bfbits(u & 0xffffu), ui = bfbits(u >> 16);
    float nr = lr * sr - li * si + ur;
    float ni = lr * si + li * sr + ui;
    sr = nr; si = ni;
    qp[(size_t)j * 1536] = (bf16)sr;
    qp[(size_t)j * 1536 + 256] = (bf16)si;
  }
  if (c == NC - 1) {
    st[(size_t)b * 256 + n] = sr;
    st[1024 + (size_t)b * 256 + n] = si;
  }
}

// ---------------- Launch ----------------
extern "C" void kernel_launch(void* const* d_in, const int* in_sizes, int n_in,
                              void* d_out, int out_size, void* d_ws, size_t ws_size,
                              hipStream_t stream) {
  const float* x      = (const float*)d_in[0];
  const float* nu_log = (const float*)d_in[1];
  const float* th_log = (const float*)d_in[2];
  const float* B_re   = (const float*)d_in[3];
  const float* B_im   = (const float*)d_in[4];
  const float* C_re   = (const float*)d_in[5];
  const float* C_im   = (const float*)d_in[6];
  const float* D_mat  = (const float*)d_in[7];
  const float* W1     = (const float*)d_in[8];
  const float* W2     = (const float*)d_in[9];
  const float* reslog = (const float*)d_in[10];

  char* wsb = (char*)d_ws;
  size_t off = 0;
  auto alloc = [&](size_t bytes) {
    void* p = wsb + off;
    off += (bytes + 255) & ~(size_t)255;
    return p;
  };
  float*  scal = (float*)alloc(5 * 256 * 4);
  bf16*   WBbu = (bf16*)alloc((size_t)512 * 1024 * 2);
  bf16*   WBy  = (bf16*)alloc((size_t)1024 * 1536 * 2);
  bf16*   WB1  = (bf16*)alloc((size_t)4096 * 1024 * 2);   // W1^T
  bf16*   WB2  = (bf16*)alloc((size_t)1024 * 4096 * 2);   // W2^T
  float2* H    = (float2*)alloc((size_t)B_ * NC * 256 * 8);
  float2* Cr   = (float2*)alloc((size_t)B_ * NC * 256 * 8);
  bf16*   Ybf  = (bf16*)alloc((size_t)BL * 1024 * 2);
  bf16*   XS   = (bf16*)alloc((size_t)BL * 1536 * 2);     // [Sr|Si|x]
  bf16*   Bu   = (bf16*)alloc((size_t)BL * 512 * 2);
  // gelu buffer (8192x4096 bf16 = 64 MB) aliases XS+Bu (dead by MLP time)
  bf16*   Hbf  = XS;

  float* out = (float*)d_out;
  float* st  = out + (size_t)BL * DM;

  phaseA<<<1, 256, 0, stream>>>(nu_log, th_log, scal);
  prep_bu<<<512 * 1024 / 256, 256, 0, stream>>>(B_re, B_im, scal, WBbu);
  prep_y<<<1024 * 1536 / 256, 256, 0, stream>>>(C_re, C_im, D_mat, WBy);
  transpose_to_bf16<<<dim3(4096 / 32, 1024 / 32), dim3(32, 8), 0, stream>>>(W1, WB1, 1024, 4096);
  transpose_to_bf16<<<dim3(1024 / 32, 4096 / 32), dim3(32, 8), 0, stream>>>(W2, WB2, 4096, 1024);
  conv_x<<<BL * 256 / 256, 256, 0, stream>>>((const float4*)x, XS);

  // Bu = x @ [gammaB]^T  (M=16384, N=512, K=1024): 128x256 tiles -> 256 blocks
  gemm128<0><<<128 * 2, 512, 0, stream>>>(
      XS + 512, 1536, WBbu, 1024, Bu, 512, 16, 128, 2, nullptr, nullptr);

  scan_pass1<<<B_ * NC, 256, 0, stream>>>(Bu, scal, H);
  scan_pass2<<<B_, 256, 0, stream>>>(H, scal, Cr);
  scan_pass3<<<B_ * NC, 256, 0, stream>>>(Bu, scal, Cr, XS, st);

  // y = [Sr|Si|x] @ [C_re|-C_im|D]^T  (M=16384, N=1024, K=1536): 256^2, 256 blk
  gemm256<0><<<64 * 4, 512, 0, stream>>>(
      XS, 1536, WBy, 1536, Ybf, 1024, 24, 64, 4, nullptr, nullptr);

  // MLP, M-chunked by 8192 rows (2 chunks)
  for (int i = 0; i < 2; i++) {
    const bf16* Yc = Ybf + (size_t)i * 8192 * 1024;
    float* Oc = out + (size_t)i * 8192 * 1024;
    const float* Xc = x + (size_t)i * 8192 * 1024;
    // MLP1: M=8192, N=4096, K=1024 -> 256^2, 512 blocks (2 rounds)
    gemm256<1><<<32 * 16, 512, 0, stream>>>(
        Yc, 1024, WB1, 1024, Hbf, 4096, 16, 32, 16, nullptr, nullptr);
    // MLP2: M=8192, N=1024, K=4096 -> 128x256 tiles, 256 blocks (full GPU)
    gemm128<2><<<64 * 4, 512, 0, stream>>>(
        Hbf, 4096, WB2, 4096, Oc, 1024, 64, 64, 4, Xc, reslog);
  }
}